// Round 1
// baseline (4728.075 us; speedup 1.0000x reference)
//
#include <hip/hip_runtime.h>
#include <cstdint>

#define TPB 256

// ---------------- degree / norm ----------------

__global__ void k_init_deg(float* deg, int n) {
  int i = blockIdx.x * blockDim.x + threadIdx.x;
  if (i < n) deg[i] = 1.0f;  // self-loop weight
}

__global__ void k_accum_deg(const int* __restrict__ col, const float* __restrict__ w,
                            float* deg, int E) {
  int e = blockIdx.x * blockDim.x + threadIdx.x;
  if (e < E) atomicAdd(&deg[col[e]], w[e]);
}

__global__ void k_rsqrt(float* d, int n) {
  int i = blockIdx.x * blockDim.x + threadIdx.x;
  if (i < n) d[i] = rsqrtf(d[i]);  // deg >= 1 always
}

__global__ void k_norm(const int* __restrict__ row, const int* __restrict__ col,
                       const float* __restrict__ w, const float* __restrict__ dis,
                       float* __restrict__ norm, int E) {
  int e = blockIdx.x * blockDim.x + threadIdx.x;
  if (e < E) norm[e] = dis[row[e]] * w[e] * dis[col[e]];
}

// ---------------- aggregation (atomic scatter) ----------------

// out[i*F + f] = dis[i]^2 * h[i*F + f]   (self-loop term), float4-granule
template<int LOGF4>
__global__ void k_self_init(const float* __restrict__ h, const float* __restrict__ dis,
                            float* __restrict__ out, int n) {
  int idx = blockIdx.x * blockDim.x + threadIdx.x;
  if (idx >= (n << LOGF4)) return;
  int i = idx >> LOGF4;
  float d = dis[i];
  float s = d * d;
  float4 v = *reinterpret_cast<const float4*>(h + ((size_t)idx << 2));
  v.x *= s; v.y *= s; v.z *= s; v.w *= s;
  *reinterpret_cast<float4*>(out + ((size_t)idx << 2)) = v;
}

template<int LOGF4>
__global__ void k_edge_agg(const int* __restrict__ row, const int* __restrict__ col,
                           const float* __restrict__ norm, const float* __restrict__ h,
                           float* __restrict__ out, int E) {
  int idx = blockIdx.x * blockDim.x + threadIdx.x;
  if (idx >= (E << LOGF4)) return;
  int e = idx >> LOGF4;
  int f4 = idx & ((1 << LOGF4) - 1);
  const int F = 4 << LOGF4;
  float nv = norm[e];
  float4 hv = *reinterpret_cast<const float4*>(h + (size_t)row[e] * F + f4 * 4);
  float* o = out + (size_t)col[e] * F + f4 * 4;
  atomicAdd(o + 0, nv * hv.x);
  atomicAdd(o + 1, nv * hv.y);
  atomicAdd(o + 2, nv * hv.z);
  atomicAdd(o + 3, nv * hv.w);
}

template<int LOGF4>
__global__ void k_bias_relu(float* __restrict__ h, const float* __restrict__ bias, int n) {
  int idx = blockIdx.x * blockDim.x + threadIdx.x;
  if (idx >= (n << LOGF4)) return;
  int f4 = idx & ((1 << LOGF4) - 1);
  float4 v = *reinterpret_cast<float4*>(h + ((size_t)idx << 2));
  float4 b = *reinterpret_cast<const float4*>(bias + f4 * 4);
  v.x = fmaxf(v.x + b.x, 0.f);
  v.y = fmaxf(v.y + b.y, 0.f);
  v.z = fmaxf(v.z + b.z, 0.f);
  v.w = fmaxf(v.w + b.w, 0.f);
  *reinterpret_cast<float4*>(h + ((size_t)idx << 2)) = v;
}

// ---------------- layer-3 aggregation directly into padded output ----------------
// out layout: [ng, npg+1, 64]; node i -> (i/npg, i%npg); row npg is zero pad.

__global__ void k_out_init(const float* __restrict__ t3, const float* __restrict__ dis,
                           const float* __restrict__ b3, float* __restrict__ out,
                           const int* __restrict__ ngp, int n, int total4) {
  int idx = blockIdx.x * blockDim.x + threadIdx.x;
  if (idx >= total4) return;
  int ng = *ngp;
  int npg = n / ng;
  int f4 = idx & 15;           // 64 feats = 16 float4
  int rg = idx >> 4;           // global padded row
  int g = rg / (npg + 1);
  int r = rg - g * (npg + 1);
  float4 v;
  if (r == npg) {
    v = make_float4(0.f, 0.f, 0.f, 0.f);
  } else {
    int i = g * npg + r;
    float d = dis[i];
    float s = d * d;
    float4 t = *reinterpret_cast<const float4*>(t3 + (size_t)i * 64 + f4 * 4);
    float4 bb = *reinterpret_cast<const float4*>(b3 + f4 * 4);
    v = make_float4(s * t.x + bb.x, s * t.y + bb.y, s * t.z + bb.z, s * t.w + bb.w);
  }
  *reinterpret_cast<float4*>(out + ((size_t)idx << 2)) = v;
}

__global__ void k_edge_agg_out(const int* __restrict__ row, const int* __restrict__ col,
                               const float* __restrict__ norm, const float* __restrict__ t3,
                               float* __restrict__ out, const int* __restrict__ ngp,
                               int E, int n) {
  int idx = blockIdx.x * blockDim.x + threadIdx.x;
  if (idx >= (E << 4)) return;
  int e = idx >> 4;
  int f4 = idx & 15;
  int ng = *ngp;
  int npg = n / ng;
  int c = col[e];
  int g = c / npg;
  int r = c - g * npg;
  size_t off = ((size_t)g * (npg + 1) + r) * 64 + f4 * 4;
  float nv = norm[e];
  float4 hv = *reinterpret_cast<const float4*>(t3 + (size_t)row[e] * 64 + f4 * 4);
  float* o = out + off;
  atomicAdd(o + 0, nv * hv.x);
  atomicAdd(o + 1, nv * hv.y);
  atomicAdd(o + 2, nv * hv.z);
  atomicAdd(o + 3, nv * hv.w);
}

// ---------------- f32 GEMM: C[N,M] = A[N,K] @ B[K,M] (+bias, relu) ----------------
// 64x64 tile, BK=32, 256 threads, 4x4 micro-tile. N%64==0, M%64==0, K%32==0.

template<bool RELU, bool BIAS>
__global__ __launch_bounds__(256) void gemm_k(const float* __restrict__ A,
                                              const float* __restrict__ B,
                                              const float* __restrict__ bias,
                                              float* __restrict__ C, int K, int M) {
  __shared__ float As[32][64];  // [k][r]  (transposed store avoids bank-serialized reads)
  __shared__ float Bs[32][64];  // [k][nn]
  const int tid = threadIdx.x;
  const int tx = tid & 15;
  const int ty = tid >> 4;
  const int rowBase = blockIdx.x * 64;
  const int colBase = blockIdx.y * 64;

  float acc[4][4] = {{0.f}};

  for (int k0 = 0; k0 < K; k0 += 32) {
    // A tile: 64 rows x 32 k = 512 float4 slots; slot s: r = s>>3, kk = s&7
#pragma unroll
    for (int t = 0; t < 2; ++t) {
      int s = t * 256 + tid;
      int r = s >> 3;
      int kk = s & 7;
      float4 v = *reinterpret_cast<const float4*>(A + (size_t)(rowBase + r) * K + k0 + kk * 4);
      As[kk * 4 + 0][r] = v.x;
      As[kk * 4 + 1][r] = v.y;
      As[kk * 4 + 2][r] = v.z;
      As[kk * 4 + 3][r] = v.w;
    }
    // B tile: 32 k x 64 cols = 512 float4 slots; slot s: kk = s>>4, nn = s&15
#pragma unroll
    for (int t = 0; t < 2; ++t) {
      int s = t * 256 + tid;
      int kk = s >> 4;
      int nn = s & 15;
      float4 v = *reinterpret_cast<const float4*>(B + (size_t)(k0 + kk) * M + colBase + nn * 4);
      *reinterpret_cast<float4*>(&Bs[kk][nn * 4]) = v;
    }
    __syncthreads();
#pragma unroll
    for (int k = 0; k < 32; ++k) {
      float a[4], b[4];
#pragma unroll
      for (int i = 0; i < 4; ++i) a[i] = As[k][ty * 4 + i];
#pragma unroll
      for (int j = 0; j < 4; ++j) b[j] = Bs[k][tx * 4 + j];
#pragma unroll
      for (int i = 0; i < 4; ++i)
#pragma unroll
        for (int j = 0; j < 4; ++j) acc[i][j] += a[i] * b[j];
    }
    __syncthreads();
  }

  float4 bb = make_float4(0.f, 0.f, 0.f, 0.f);
  if (BIAS) bb = *reinterpret_cast<const float4*>(bias + colBase + tx * 4);
#pragma unroll
  for (int i = 0; i < 4; ++i) {
    int r = rowBase + ty * 4 + i;
    float4 v = make_float4(acc[i][0], acc[i][1], acc[i][2], acc[i][3]);
    if (BIAS) { v.x += bb.x; v.y += bb.y; v.z += bb.z; v.w += bb.w; }
    if (RELU) {
      v.x = fmaxf(v.x, 0.f); v.y = fmaxf(v.y, 0.f);
      v.z = fmaxf(v.z, 0.f); v.w = fmaxf(v.w, 0.f);
    }
    *reinterpret_cast<float4*>(C + (size_t)r * M + colBase + tx * 4) = v;
  }
}

// ---------------- launch ----------------

static inline int nblk(long work, int tpb = TPB) { return (int)((work + tpb - 1) / tpb); }

extern "C" void kernel_launch(void* const* d_in, const int* in_sizes, int n_in,
                              void* d_out, int out_size, void* d_ws, size_t ws_size,
                              hipStream_t stream) {
  const float* x  = (const float*)d_in[0];
  const int*   ei = (const int*)d_in[1];
  const float* ew = (const float*)d_in[2];
  const int*  ngp = (const int*)d_in[3];
  const float* W1 = (const float*)d_in[4];
  const float* b1 = (const float*)d_in[5];
  const float* W2 = (const float*)d_in[6];
  const float* b2 = (const float*)d_in[7];
  const float* W3 = (const float*)d_in[8];
  const float* b3 = (const float*)d_in[9];
  float* out = (float*)d_out;

  const int n = in_sizes[0] / 128;  // 65536
  const int E = in_sizes[2];        // 1048576
  const int* row = ei;
  const int* col = ei + E;

  float* ws   = (float*)d_ws;
  float* norm = ws;                       // E
  float* dis  = norm + E;                 // n
  float* buf1 = dis + n;                  // n*256 (h1)
  float* buf2 = buf1 + (size_t)n * 256;   // n*128 (t1 / t2 / t3)
  float* buf3 = buf2 + (size_t)n * 128;   // n*128 (a2/h2)

  // norm precompute (deg stored in dis, then rsqrt'd in place)
  k_init_deg<<<nblk(n), TPB, 0, stream>>>(dis, n);
  k_accum_deg<<<nblk(E), TPB, 0, stream>>>(col, ew, dis, E);
  k_rsqrt<<<nblk(n), TPB, 0, stream>>>(dis, n);
  k_norm<<<nblk(E), TPB, 0, stream>>>(row, col, ew, dis, norm, E);

  // ---- layer 1: t1 = A(x)  [n,128] in buf2; h1 = relu(t1@W1+b1) [n,256] in buf1
  k_self_init<5><<<nblk((long)n * 32), TPB, 0, stream>>>(x, dis, buf2, n);
  k_edge_agg<5><<<nblk((long)E * 32), TPB, 0, stream>>>(row, col, norm, x, buf2, E);
  {
    dim3 g(n / 64, 256 / 64);
    gemm_k<true, true><<<g, 256, 0, stream>>>(buf2, W1, b1, buf1, 128, 256);
  }

  // ---- layer 2: t2 = h1@W2 [n,128] in buf2; a2 = A(t2) in buf3; h2 = relu(a2+b2)
  {
    dim3 g(n / 64, 128 / 64);
    gemm_k<false, false><<<g, 256, 0, stream>>>(buf1, W2, nullptr, buf2, 256, 128);
  }
  k_self_init<5><<<nblk((long)n * 32), TPB, 0, stream>>>(buf2, dis, buf3, n);
  k_edge_agg<5><<<nblk((long)E * 32), TPB, 0, stream>>>(row, col, norm, buf2, buf3, E);
  k_bias_relu<5><<<nblk((long)n * 32), TPB, 0, stream>>>(buf3, b2, n);

  // ---- layer 3: t3 = h2@W3 [n,64] in buf2; out = A(t3) + b3 into padded layout
  {
    dim3 g(n / 64, 64 / 64);
    gemm_k<false, false><<<g, 256, 0, stream>>>(buf3, W3, nullptr, buf2, 128, 64);
  }
  k_out_init<<<nblk((long)out_size / 4), TPB, 0, stream>>>(buf2, dis, b3, out, ngp, n, out_size / 4);
  k_edge_agg_out<<<nblk((long)E * 16), TPB, 0, stream>>>(row, col, norm, buf2, out, ngp, E, n);
}

// Round 2
// 728.993 us; speedup vs baseline: 6.4858x; 6.4858x over previous
//
#include <hip/hip_runtime.h>
#include <cstdint>

#define TPB 256

// ================= CSR build (sort edges by target col) =================

__global__ void k_count(const int* __restrict__ col, int* __restrict__ cnt, int E) {
  int e = blockIdx.x * blockDim.x + threadIdx.x;
  if (e < E) atomicAdd(&cnt[col[e]], 1);
}

// single block, 256 threads; n % 256 == 0. Writes ptr[0..n] and cur[0..n-1].
__global__ void k_scan(const int* __restrict__ cnt, int* __restrict__ ptr,
                       int* __restrict__ cur, int n) {
  __shared__ int sums[256];
  __shared__ int offs[256];
  const int t = threadIdx.x;
  const int chunk = n / 256;
  int s = 0;
  for (int j = 0; j < chunk; ++j) s += cnt[t * chunk + j];
  sums[t] = s;
  __syncthreads();
  if (t == 0) {
    int o = 0;
    for (int i = 0; i < 256; ++i) { offs[i] = o; o += sums[i]; }
  }
  __syncthreads();
  int o = offs[t];
  for (int j = 0; j < chunk; ++j) {
    int idx = t * chunk + j;
    int c = cnt[idx];
    ptr[idx] = o;
    cur[idx] = o;
    o += c;
  }
  if (t == 255) ptr[n] = o;
}

__global__ void k_scatter(const int* __restrict__ row, const int* __restrict__ col,
                          const float* __restrict__ w, int* __restrict__ cur,
                          int* __restrict__ row_s, int* __restrict__ col_s,
                          float* __restrict__ w_s, int E) {
  int e = blockIdx.x * blockDim.x + threadIdx.x;
  if (e >= E) return;
  int c = col[e];
  int p = atomicAdd(&cur[c], 1);
  row_s[p] = row[e];
  col_s[p] = c;
  w_s[p] = w[e];
}

// dis[i] = rsqrt(1 + sum_in w)
__global__ void k_deg(const int* __restrict__ ptr, const float* __restrict__ w_s,
                      float* __restrict__ dis, int n) {
  int i = blockIdx.x * blockDim.x + threadIdx.x;
  if (i >= n) return;
  float d = 1.0f;
  int e0 = ptr[i], e1 = ptr[i + 1];
  for (int e = e0; e < e1; ++e) d += w_s[e];
  dis[i] = rsqrtf(d);
}

// w_s[e] <- dis[row]*w*dis[col]  (in place)
__global__ void k_normip(const int* __restrict__ row_s, const int* __restrict__ col_s,
                         float* __restrict__ w_s, const float* __restrict__ dis, int E) {
  int e = blockIdx.x * blockDim.x + threadIdx.x;
  if (e < E) w_s[e] = dis[row_s[e]] * w_s[e] * dis[col_s[e]];
}

// ================= gather aggregation =================
// One GL-lane group per destination node; lane owns one float4 column.
// out[i] = dis[i]^2 * h[i] + sum_e norm[e]*h[row[e]]  (+bias, relu optional)

template<int GL, bool RELU, bool BIAS>
__global__ __launch_bounds__(256) void k_gagg(const int* __restrict__ ptr,
                                              const int* __restrict__ row_s,
                                              const float* __restrict__ norm_s,
                                              const float* __restrict__ h,
                                              const float* __restrict__ dis,
                                              const float* __restrict__ bias,
                                              float* __restrict__ out, int n) {
  constexpr int GPB = 256 / GL;
  const int gid = blockIdx.x * GPB + threadIdx.x / GL;
  const int lane = threadIdx.x % GL;
  if (gid >= n) return;
  constexpr int F = GL * 4;
  const int e0 = ptr[gid], e1 = ptr[gid + 1];
  float d = dis[gid];
  float ss = d * d;
  float4 acc = *reinterpret_cast<const float4*>(h + (size_t)gid * F + lane * 4);
  acc.x *= ss; acc.y *= ss; acc.z *= ss; acc.w *= ss;
  for (int e = e0; e < e1; ++e) {
    float nv = norm_s[e];          // broadcast within group
    int r = row_s[e];              // broadcast within group
    float4 v = *reinterpret_cast<const float4*>(h + (size_t)r * F + lane * 4);
    acc.x += nv * v.x; acc.y += nv * v.y; acc.z += nv * v.z; acc.w += nv * v.w;
  }
  if (BIAS) {
    float4 bb = *reinterpret_cast<const float4*>(bias + lane * 4);
    acc.x += bb.x; acc.y += bb.y; acc.z += bb.z; acc.w += bb.w;
  }
  if (RELU) {
    acc.x = fmaxf(acc.x, 0.f); acc.y = fmaxf(acc.y, 0.f);
    acc.z = fmaxf(acc.z, 0.f); acc.w = fmaxf(acc.w, 0.f);
  }
  *reinterpret_cast<float4*>(out + (size_t)gid * F + lane * 4) = acc;
}

// Layer-3 aggregation (F=64) directly into padded [ng, npg+1, 64] output, +b3.
__global__ __launch_bounds__(256) void k_gagg_out(const int* __restrict__ ptr,
                                                  const int* __restrict__ row_s,
                                                  const float* __restrict__ norm_s,
                                                  const float* __restrict__ t3,
                                                  const float* __restrict__ dis,
                                                  const float* __restrict__ b3,
                                                  float* __restrict__ out,
                                                  const int* __restrict__ ngp,
                                                  int n, int nrows) {
  const int gid = blockIdx.x * 16 + threadIdx.x / 16;  // padded row index
  const int lane = threadIdx.x % 16;
  if (gid >= nrows) return;
  const int ng = *ngp;
  const int npg = n / ng;
  const int g = gid / (npg + 1);
  const int r = gid - g * (npg + 1);
  float4 acc = make_float4(0.f, 0.f, 0.f, 0.f);
  if (r < npg) {
    const int i = g * npg + r;
    const int e0 = ptr[i], e1 = ptr[i + 1];
    float d = dis[i];
    float ss = d * d;
    acc = *reinterpret_cast<const float4*>(t3 + (size_t)i * 64 + lane * 4);
    acc.x *= ss; acc.y *= ss; acc.z *= ss; acc.w *= ss;
    for (int e = e0; e < e1; ++e) {
      float nv = norm_s[e];
      int rr = row_s[e];
      float4 v = *reinterpret_cast<const float4*>(t3 + (size_t)rr * 64 + lane * 4);
      acc.x += nv * v.x; acc.y += nv * v.y; acc.z += nv * v.z; acc.w += nv * v.w;
    }
    float4 bb = *reinterpret_cast<const float4*>(b3 + lane * 4);
    acc.x += bb.x; acc.y += bb.y; acc.z += bb.z; acc.w += bb.w;
  }
  *reinterpret_cast<float4*>(out + (size_t)gid * 64 + lane * 4) = acc;
}

// ================= f32 GEMM: C[N,M] = A[N,K] @ B[K,M] (+bias, relu) =================
// 64x64 tile, BK=32, 256 threads, 4x4 micro-tile. N%64==0, M%64==0, K%32==0.

template<bool RELU, bool BIAS>
__global__ __launch_bounds__(256) void gemm_k(const float* __restrict__ A,
                                              const float* __restrict__ B,
                                              const float* __restrict__ bias,
                                              float* __restrict__ C, int K, int M) {
  __shared__ float As[32][64];  // [k][r]
  __shared__ float Bs[32][64];  // [k][nn]
  const int tid = threadIdx.x;
  const int tx = tid & 15;
  const int ty = tid >> 4;
  const int rowBase = blockIdx.x * 64;
  const int colBase = blockIdx.y * 64;

  float acc[4][4] = {{0.f}};

  for (int k0 = 0; k0 < K; k0 += 32) {
#pragma unroll
    for (int t = 0; t < 2; ++t) {
      int s = t * 256 + tid;
      int r = s >> 3;
      int kk = s & 7;
      float4 v = *reinterpret_cast<const float4*>(A + (size_t)(rowBase + r) * K + k0 + kk * 4);
      As[kk * 4 + 0][r] = v.x;
      As[kk * 4 + 1][r] = v.y;
      As[kk * 4 + 2][r] = v.z;
      As[kk * 4 + 3][r] = v.w;
    }
#pragma unroll
    for (int t = 0; t < 2; ++t) {
      int s = t * 256 + tid;
      int kk = s >> 4;
      int nn = s & 15;
      float4 v = *reinterpret_cast<const float4*>(B + (size_t)(k0 + kk) * M + colBase + nn * 4);
      *reinterpret_cast<float4*>(&Bs[kk][nn * 4]) = v;
    }
    __syncthreads();
#pragma unroll
    for (int k = 0; k < 32; ++k) {
      float a[4], b[4];
#pragma unroll
      for (int i = 0; i < 4; ++i) a[i] = As[k][ty * 4 + i];
#pragma unroll
      for (int j = 0; j < 4; ++j) b[j] = Bs[k][tx * 4 + j];
#pragma unroll
      for (int i = 0; i < 4; ++i)
#pragma unroll
        for (int j = 0; j < 4; ++j) acc[i][j] += a[i] * b[j];
    }
    __syncthreads();
  }

  float4 bb = make_float4(0.f, 0.f, 0.f, 0.f);
  if (BIAS) bb = *reinterpret_cast<const float4*>(bias + colBase + tx * 4);
#pragma unroll
  for (int i = 0; i < 4; ++i) {
    int r = rowBase + ty * 4 + i;
    float4 v = make_float4(acc[i][0], acc[i][1], acc[i][2], acc[i][3]);
    if (BIAS) { v.x += bb.x; v.y += bb.y; v.z += bb.z; v.w += bb.w; }
    if (RELU) {
      v.x = fmaxf(v.x, 0.f); v.y = fmaxf(v.y, 0.f);
      v.z = fmaxf(v.z, 0.f); v.w = fmaxf(v.w, 0.f);
    }
    *reinterpret_cast<float4*>(C + (size_t)r * M + colBase + tx * 4) = v;
  }
}

// ================= launch =================

static inline int nblk(long work, int tpb = TPB) { return (int)((work + tpb - 1) / tpb); }

extern "C" void kernel_launch(void* const* d_in, const int* in_sizes, int n_in,
                              void* d_out, int out_size, void* d_ws, size_t ws_size,
                              hipStream_t stream) {
  const float* x  = (const float*)d_in[0];
  const int*   ei = (const int*)d_in[1];
  const float* ew = (const float*)d_in[2];
  const int*  ngp = (const int*)d_in[3];
  const float* W1 = (const float*)d_in[4];
  const float* b1 = (const float*)d_in[5];
  const float* W2 = (const float*)d_in[6];
  const float* b2 = (const float*)d_in[7];
  const float* W3 = (const float*)d_in[8];
  const float* b3 = (const float*)d_in[9];
  float* out = (float*)d_out;

  const int n = in_sizes[0] / 128;  // 65536
  const int E = in_sizes[2];        // 1048576
  const int* row = ei;
  const int* col = ei + E;

  // workspace layout
  int* wi = (int*)d_ws;
  int* cnt   = wi;                  // n
  int* ptr   = cnt + n;             // n+1
  int* cur   = ptr + (n + 1);       // n
  int* row_s = cur + n;             // E
  int* col_s = row_s + E;           // E
  float* w_s = (float*)(col_s + E); // E (becomes norm in place)
  float* dis = w_s + E;             // n
  float* buf1 = dis + n;            // n*256
  float* buf2 = buf1 + (size_t)n * 256;  // n*128
  float* buf3 = buf2 + (size_t)n * 128;  // n*128

  // ---- CSR build
  hipMemsetAsync(cnt, 0, (size_t)n * sizeof(int), stream);
  k_count<<<nblk(E), TPB, 0, stream>>>(col, cnt, E);
  k_scan<<<1, 256, 0, stream>>>(cnt, ptr, cur, n);
  k_scatter<<<nblk(E), TPB, 0, stream>>>(row, col, ew, cur, row_s, col_s, w_s, E);
  k_deg<<<nblk(n), TPB, 0, stream>>>(ptr, w_s, dis, n);
  k_normip<<<nblk(E), TPB, 0, stream>>>(row_s, col_s, w_s, dis, E);

  // ---- layer 1: t1 = A(x) [n,128] -> buf2 ; h1 = relu(t1@W1+b1) [n,256] -> buf1
  k_gagg<32, false, false><<<nblk((long)n * 32), TPB, 0, stream>>>(
      ptr, row_s, w_s, x, dis, nullptr, buf2, n);
  {
    dim3 g(n / 64, 256 / 64);
    gemm_k<true, true><<<g, 256, 0, stream>>>(buf2, W1, b1, buf1, 128, 256);
  }

  // ---- layer 2: t2 = h1@W2 [n,128] -> buf2 ; h2 = relu(A(t2)+b2) -> buf3
  {
    dim3 g(n / 64, 128 / 64);
    gemm_k<false, false><<<g, 256, 0, stream>>>(buf1, W2, nullptr, buf2, 256, 128);
  }
  k_gagg<32, true, true><<<nblk((long)n * 32), TPB, 0, stream>>>(
      ptr, row_s, w_s, buf2, dis, b2, buf3, n);

  // ---- layer 3: t3 = h2@W3 [n,64] -> buf2 ; out = A(t3)+b3 into padded layout
  {
    dim3 g(n / 64, 64 / 64);
    gemm_k<false, false><<<g, 256, 0, stream>>>(buf3, W3, nullptr, buf2, 128, 64);
  }
  const int nrows = out_size / 64;  // ng*(npg+1)
  k_gagg_out<<<nblk((long)nrows * 16), TPB, 0, stream>>>(
      ptr, row_s, w_s, buf2, dis, b3, out, ngp, n, nrows);
}

// Round 3
// 631.009 us; speedup vs baseline: 7.4929x; 1.1553x over previous
//
#include <hip/hip_runtime.h>
#include <cstdint>

#define TPB 256

// ================= degree + count =================

__global__ void k_init(int* __restrict__ cnt, float* __restrict__ deg, int n) {
  int i = blockIdx.x * blockDim.x + threadIdx.x;
  if (i < n) { cnt[i] = 0; deg[i] = 1.0f; }  // self-loop weight
}

__global__ void k_count_deg(const int* __restrict__ col, const float* __restrict__ w,
                            int* __restrict__ cnt, float* __restrict__ deg, int E) {
  int e = blockIdx.x * blockDim.x + threadIdx.x;
  if (e >= E) return;
  int c = col[e];
  atomicAdd(&cnt[c], 1);
  atomicAdd(&deg[c], w[e]);
}

__global__ void k_rsqrt(float* d, int n) {
  int i = blockIdx.x * blockDim.x + threadIdx.x;
  if (i < n) d[i] = rsqrtf(d[i]);  // deg >= 1 always
}

// ================= parallel scan of cnt[n] -> ptr[n+1], cur[n] =================

__global__ void k_reduceA(const int* __restrict__ cnt, int* __restrict__ bsum) {
  __shared__ int s[256];
  int t = threadIdx.x;
  s[t] = cnt[blockIdx.x * 256 + t];
  __syncthreads();
  for (int st = 128; st > 0; st >>= 1) {
    if (t < st) s[t] += s[t + st];
    __syncthreads();
  }
  if (t == 0) bsum[blockIdx.x] = s[0];
}

__global__ void k_scanB(const int* __restrict__ bsum, int* __restrict__ boff) {
  __shared__ int s[256];
  int t = threadIdx.x;
  int v = bsum[t];
  s[t] = v;
  __syncthreads();
  for (int st = 1; st < 256; st <<= 1) {
    int a = (t >= st) ? s[t - st] : 0;
    __syncthreads();
    s[t] += a;
    __syncthreads();
  }
  boff[t] = s[t] - v;  // exclusive
}

__global__ void k_scanC(const int* __restrict__ cnt, const int* __restrict__ boff,
                        int* __restrict__ ptr, int* __restrict__ cur, int n) {
  __shared__ int s[256];
  int t = threadIdx.x;
  int i = blockIdx.x * 256 + t;
  int v = cnt[i];
  s[t] = v;
  __syncthreads();
  for (int st = 1; st < 256; st <<= 1) {
    int a = (t >= st) ? s[t - st] : 0;
    __syncthreads();
    s[t] += a;
    __syncthreads();
  }
  int excl = boff[blockIdx.x] + s[t] - v;
  ptr[i] = excl;
  cur[i] = excl;
  if (i == n - 1) ptr[n] = excl + v;
}

// ================= scatter with fused norm =================
// edat[p] = (row, dis[row]*w*dis[col]) sorted by col

__global__ void k_scatter_norm(const int* __restrict__ row, const int* __restrict__ col,
                               const float* __restrict__ w, const float* __restrict__ dis,
                               int* __restrict__ cur, int2* __restrict__ edat, int E) {
  int e = blockIdx.x * blockDim.x + threadIdx.x;
  if (e >= E) return;
  int c = col[e];
  int r = row[e];
  float nv = dis[r] * w[e] * dis[c];
  int p = atomicAdd(&cur[c], 1);
  edat[p] = make_int2(r, __float_as_int(nv));
}

// ================= gather aggregation =================
// One GL-lane group per destination node; lane owns one float4 column.
// out[i] = dis[i]^2 * h[i] + sum_e norm[e]*h[row[e]]  (+bias, relu optional)

template<int GL, bool RELU, bool BIAS>
__global__ __launch_bounds__(256) void k_gagg(const int* __restrict__ ptr,
                                              const int2* __restrict__ edat,
                                              const float* __restrict__ h,
                                              const float* __restrict__ dis,
                                              const float* __restrict__ bias,
                                              float* __restrict__ out, int n) {
  constexpr int GPB = 256 / GL;
  const int gid = blockIdx.x * GPB + threadIdx.x / GL;
  const int lane = threadIdx.x % GL;
  if (gid >= n) return;
  constexpr int F = GL * 4;
  const int e0 = ptr[gid], e1 = ptr[gid + 1];
  float d = dis[gid];
  float ss = d * d;
  float4 acc = *reinterpret_cast<const float4*>(h + (size_t)gid * F + lane * 4);
  acc.x *= ss; acc.y *= ss; acc.z *= ss; acc.w *= ss;
  for (int e = e0; e < e1; ++e) {
    int2 ed = edat[e];
    float nv = __int_as_float(ed.y);
    float4 v = *reinterpret_cast<const float4*>(h + (size_t)ed.x * F + lane * 4);
    acc.x += nv * v.x; acc.y += nv * v.y; acc.z += nv * v.z; acc.w += nv * v.w;
  }
  if (BIAS) {
    float4 bb = *reinterpret_cast<const float4*>(bias + lane * 4);
    acc.x += bb.x; acc.y += bb.y; acc.z += bb.z; acc.w += bb.w;
  }
  if (RELU) {
    acc.x = fmaxf(acc.x, 0.f); acc.y = fmaxf(acc.y, 0.f);
    acc.z = fmaxf(acc.z, 0.f); acc.w = fmaxf(acc.w, 0.f);
  }
  *reinterpret_cast<float4*>(out + (size_t)gid * F + lane * 4) = acc;
}

// Layer-3 aggregation (F=64) directly into padded [ng, npg+1, 64] output, +b3.
__global__ __launch_bounds__(256) void k_gagg_out(const int* __restrict__ ptr,
                                                  const int2* __restrict__ edat,
                                                  const float* __restrict__ t3,
                                                  const float* __restrict__ dis,
                                                  const float* __restrict__ b3,
                                                  float* __restrict__ out,
                                                  const int* __restrict__ ngp,
                                                  int n, int nrows) {
  const int gid = blockIdx.x * 16 + threadIdx.x / 16;  // padded row index
  const int lane = threadIdx.x % 16;
  if (gid >= nrows) return;
  const int ng = *ngp;
  const int npg = n / ng;
  const int g = gid / (npg + 1);
  const int r = gid - g * (npg + 1);
  float4 acc = make_float4(0.f, 0.f, 0.f, 0.f);
  if (r < npg) {
    const int i = g * npg + r;
    const int e0 = ptr[i], e1 = ptr[i + 1];
    float d = dis[i];
    float ss = d * d;
    acc = *reinterpret_cast<const float4*>(t3 + (size_t)i * 64 + lane * 4);
    acc.x *= ss; acc.y *= ss; acc.z *= ss; acc.w *= ss;
    for (int e = e0; e < e1; ++e) {
      int2 ed = edat[e];
      float nv = __int_as_float(ed.y);
      float4 v = *reinterpret_cast<const float4*>(t3 + (size_t)ed.x * 64 + lane * 4);
      acc.x += nv * v.x; acc.y += nv * v.y; acc.z += nv * v.z; acc.w += nv * v.w;
    }
    float4 bb = *reinterpret_cast<const float4*>(b3 + lane * 4);
    acc.x += bb.x; acc.y += bb.y; acc.z += bb.z; acc.w += bb.w;
  }
  *reinterpret_cast<float4*>(out + (size_t)gid * 64 + lane * 4) = acc;
}

// ================= f32 GEMM: C[N,M] = A[N,K] @ B[K,M] (+bias, relu) =================
// 64x64 tile, BK=32, 256 threads, 4x4 micro-tile. N%64==0, M%64==0, K%32==0.

template<bool RELU, bool BIAS>
__global__ __launch_bounds__(256) void gemm_k(const float* __restrict__ A,
                                              const float* __restrict__ B,
                                              const float* __restrict__ bias,
                                              float* __restrict__ C, int K, int M) {
  __shared__ float As[32][64];  // [k][r]
  __shared__ float Bs[32][64];  // [k][nn]
  const int tid = threadIdx.x;
  const int tx = tid & 15;
  const int ty = tid >> 4;
  const int rowBase = blockIdx.x * 64;
  const int colBase = blockIdx.y * 64;

  float acc[4][4] = {{0.f}};

  for (int k0 = 0; k0 < K; k0 += 32) {
#pragma unroll
    for (int t = 0; t < 2; ++t) {
      int s = t * 256 + tid;
      int r = s >> 3;
      int kk = s & 7;
      float4 v = *reinterpret_cast<const float4*>(A + (size_t)(rowBase + r) * K + k0 + kk * 4);
      As[kk * 4 + 0][r] = v.x;
      As[kk * 4 + 1][r] = v.y;
      As[kk * 4 + 2][r] = v.z;
      As[kk * 4 + 3][r] = v.w;
    }
#pragma unroll
    for (int t = 0; t < 2; ++t) {
      int s = t * 256 + tid;
      int kk = s >> 4;
      int nn = s & 15;
      float4 v = *reinterpret_cast<const float4*>(B + (size_t)(k0 + kk) * M + colBase + nn * 4);
      *reinterpret_cast<float4*>(&Bs[kk][nn * 4]) = v;
    }
    __syncthreads();
#pragma unroll
    for (int k = 0; k < 32; ++k) {
      float a[4], b[4];
#pragma unroll
      for (int i = 0; i < 4; ++i) a[i] = As[k][ty * 4 + i];
#pragma unroll
      for (int j = 0; j < 4; ++j) b[j] = Bs[k][tx * 4 + j];
#pragma unroll
      for (int i = 0; i < 4; ++i)
#pragma unroll
        for (int j = 0; j < 4; ++j) acc[i][j] += a[i] * b[j];
    }
    __syncthreads();
  }

  float4 bb = make_float4(0.f, 0.f, 0.f, 0.f);
  if (BIAS) bb = *reinterpret_cast<const float4*>(bias + colBase + tx * 4);
#pragma unroll
  for (int i = 0; i < 4; ++i) {
    int r = rowBase + ty * 4 + i;
    float4 v = make_float4(acc[i][0], acc[i][1], acc[i][2], acc[i][3]);
    if (BIAS) { v.x += bb.x; v.y += bb.y; v.z += bb.z; v.w += bb.w; }
    if (RELU) {
      v.x = fmaxf(v.x, 0.f); v.y = fmaxf(v.y, 0.f);
      v.z = fmaxf(v.z, 0.f); v.w = fmaxf(v.w, 0.f);
    }
    *reinterpret_cast<float4*>(C + (size_t)r * M + colBase + tx * 4) = v;
  }
}

// ================= launch =================

static inline int nblk(long work, int tpb = TPB) { return (int)((work + tpb - 1) / tpb); }

extern "C" void kernel_launch(void* const* d_in, const int* in_sizes, int n_in,
                              void* d_out, int out_size, void* d_ws, size_t ws_size,
                              hipStream_t stream) {
  const float* x  = (const float*)d_in[0];
  const int*   ei = (const int*)d_in[1];
  const float* ew = (const float*)d_in[2];
  const int*  ngp = (const int*)d_in[3];
  const float* W1 = (const float*)d_in[4];
  const float* b1 = (const float*)d_in[5];
  const float* W2 = (const float*)d_in[6];
  const float* b2 = (const float*)d_in[7];
  const float* W3 = (const float*)d_in[8];
  const float* b3 = (const float*)d_in[9];
  float* out = (float*)d_out;

  const int n = in_sizes[0] / 128;  // 65536
  const int E = in_sizes[2];        // 1048576
  const int* row = ei;
  const int* col = ei + E;

  // workspace layout (edat first: 8B aligned)
  int2* edat = (int2*)d_ws;              // E int2
  int* cnt   = (int*)(edat + E);         // n
  int* ptr   = cnt + n;                  // n+1
  int* cur   = ptr + (n + 1);            // n
  int* bsum  = cur + n;                  // 256
  int* boff  = bsum + 256;               // 256
  float* dis = (float*)(boff + 256);     // n  (deg, then rsqrt in place)
  float* buf1 = dis + n;                 // n*256
  float* buf2 = buf1 + (size_t)n * 256;  // n*128
  float* buf3 = buf2 + (size_t)n * 128;  // n*128

  // ---- CSR build + norms
  k_init<<<nblk(n), TPB, 0, stream>>>(cnt, dis, n);
  k_count_deg<<<nblk(E), TPB, 0, stream>>>(col, ew, cnt, dis, E);
  k_rsqrt<<<nblk(n), TPB, 0, stream>>>(dis, n);
  k_reduceA<<<n / 256, 256, 0, stream>>>(cnt, bsum);
  k_scanB<<<1, 256, 0, stream>>>(bsum, boff);
  k_scanC<<<n / 256, 256, 0, stream>>>(cnt, boff, ptr, cur, n);
  k_scatter_norm<<<nblk(E), TPB, 0, stream>>>(row, col, ew, dis, cur, edat, E);

  // ---- layer 1: t1 = A(x) [n,128] -> buf2 ; h1 = relu(t1@W1+b1) [n,256] -> buf1
  k_gagg<32, false, false><<<nblk((long)n * 32), TPB, 0, stream>>>(
      ptr, edat, x, dis, nullptr, buf2, n);
  {
    dim3 g(n / 64, 256 / 64);
    gemm_k<true, true><<<g, 256, 0, stream>>>(buf2, W1, b1, buf1, 128, 256);
  }

  // ---- layer 2: t2 = h1@W2 [n,128] -> buf2 ; h2 = relu(A(t2)+b2) -> buf3
  {
    dim3 g(n / 64, 128 / 64);
    gemm_k<false, false><<<g, 256, 0, stream>>>(buf1, W2, nullptr, buf2, 256, 128);
  }
  k_gagg<32, true, true><<<nblk((long)n * 32), TPB, 0, stream>>>(
      ptr, edat, buf2, dis, b2, buf3, n);

  // ---- layer 3: t3 = h2@W3 [n,64] -> buf2 ; out = A(t3)+b3 into padded layout
  {
    dim3 g(n / 64, 64 / 64);
    gemm_k<false, false><<<g, 256, 0, stream>>>(buf3, W3, nullptr, buf2, 128, 64);
  }
  const int nrows = out_size / 64;  // ng*(npg+1)
  k_gagg_out<<<nblk((long)nrows * 16), TPB, 0, stream>>>(
      ptr, edat, buf2, dis, b3, out, ngp, n, nrows);
}

// Round 4
// 525.207 us; speedup vs baseline: 9.0023x; 1.2014x over previous
//
#include <hip/hip_runtime.h>
#include <cstdint>

#define TPB 256

typedef __attribute__((ext_vector_type(8))) short bf16x8;
typedef __attribute__((ext_vector_type(4))) float f32x4;

__device__ inline unsigned short f2bf(float f) {
  unsigned u = __float_as_uint(f);
  u += 0x7fffu + ((u >> 16) & 1u);
  return (unsigned short)(u >> 16);
}
__device__ inline float bf2f(unsigned short h) {
  return __uint_as_float(((unsigned)h) << 16);
}

__device__ inline void gload_lds16(const void* g, void* l) {
  __builtin_amdgcn_global_load_lds(
      (const __attribute__((address_space(1))) unsigned int*)g,
      (__attribute__((address_space(3))) unsigned int*)l, 16, 0, 0);
}

// ================= degree + count =================

__global__ void k_init(int* __restrict__ cnt, float* __restrict__ deg, int n) {
  int i = blockIdx.x * blockDim.x + threadIdx.x;
  if (i < n) { cnt[i] = 0; deg[i] = 1.0f; }
}

__global__ void k_count_deg(const int* __restrict__ col, const float* __restrict__ w,
                            int* __restrict__ cnt, float* __restrict__ deg, int E) {
  int e = blockIdx.x * blockDim.x + threadIdx.x;
  if (e >= E) return;
  int c = col[e];
  atomicAdd(&cnt[c], 1);
  atomicAdd(&deg[c], w[e]);
}

__global__ void k_rsqrt(float* d, int n) {
  int i = blockIdx.x * blockDim.x + threadIdx.x;
  if (i < n) d[i] = rsqrtf(d[i]);
}

// ================= parallel scan =================

__global__ void k_reduceA(const int* __restrict__ cnt, int* __restrict__ bsum) {
  __shared__ int s[256];
  int t = threadIdx.x;
  s[t] = cnt[blockIdx.x * 256 + t];
  __syncthreads();
  for (int st = 128; st > 0; st >>= 1) {
    if (t < st) s[t] += s[t + st];
    __syncthreads();
  }
  if (t == 0) bsum[blockIdx.x] = s[0];
}

__global__ void k_scanB(const int* __restrict__ bsum, int* __restrict__ boff) {
  __shared__ int s[256];
  int t = threadIdx.x;
  int v = bsum[t];
  s[t] = v;
  __syncthreads();
  for (int st = 1; st < 256; st <<= 1) {
    int a = (t >= st) ? s[t - st] : 0;
    __syncthreads();
    s[t] += a;
    __syncthreads();
  }
  boff[t] = s[t] - v;
}

__global__ void k_scanC(const int* __restrict__ cnt, const int* __restrict__ boff,
                        int* __restrict__ ptr, int* __restrict__ cur, int n) {
  __shared__ int s[256];
  int t = threadIdx.x;
  int i = blockIdx.x * 256 + t;
  int v = cnt[i];
  s[t] = v;
  __syncthreads();
  for (int st = 1; st < 256; st <<= 1) {
    int a = (t >= st) ? s[t - st] : 0;
    __syncthreads();
    s[t] += a;
    __syncthreads();
  }
  int excl = boff[blockIdx.x] + s[t] - v;
  ptr[i] = excl;
  cur[i] = excl;
  if (i == n - 1) ptr[n] = excl + v;
}

// ================= scatter with fused norm =================

__global__ void k_scatter_norm(const int* __restrict__ row, const int* __restrict__ col,
                               const float* __restrict__ w, const float* __restrict__ dis,
                               int* __restrict__ cur, int2* __restrict__ edat, int E) {
  int e = blockIdx.x * blockDim.x + threadIdx.x;
  if (e >= E) return;
  int c = col[e];
  int r = row[e];
  float nv = dis[r] * w[e] * dis[c];
  int p = atomicAdd(&cur[c], 1);
  edat[p] = make_int2(r, __float_as_int(nv));
}

// ================= W fragment prep =================
// Bfrag layout: idx = ((ks*(M/16) + c0t)*64 + lane)*8 + j
// value = W[ks*32 + (lane>>4)*8 + j][c0t*16 + (lane&15)]  split into hi/lo bf16.

__global__ void k_wprep(const float* __restrict__ W, unsigned short* __restrict__ Fhi,
                        unsigned short* __restrict__ Flo, int K, int M) {
  int t = blockIdx.x * blockDim.x + threadIdx.x;
  int total = (K >> 5) * (M >> 4) * 64;
  if (t >= total) return;
  int l = t & 63;
  int rest = t >> 6;
  int nt16 = M >> 4;
  int c0t = rest % nt16;
  int ks = rest / nt16;
  int colg = c0t * 16 + (l & 15);
  int krow = (ks << 5) + ((l >> 4) << 3);
  size_t ob = (size_t)t * 8;
#pragma unroll
  for (int j = 0; j < 8; ++j) {
    float f = W[(size_t)(krow + j) * M + colg];
    unsigned short h = f2bf(f);
    Fhi[ob + j] = h;
    Flo[ob + j] = f2bf(f - bf2f(h));
  }
}

// ================= gather aggregation (4x unrolled) =================

template<int GL, bool RELU, bool BIAS, bool OUTP>
__global__ __launch_bounds__(256) void k_gagg(const int* __restrict__ ptr,
                                              const int2* __restrict__ edat,
                                              const float* __restrict__ h,
                                              const float* __restrict__ dis,
                                              const float* __restrict__ bias,
                                              float* __restrict__ outf,
                                              unsigned short* __restrict__ ohi,
                                              unsigned short* __restrict__ olo, int n) {
  constexpr int GPB = 256 / GL;
  const int gid = blockIdx.x * GPB + threadIdx.x / GL;
  const int lane = threadIdx.x % GL;
  if (gid >= n) return;
  constexpr int F = GL * 4;
  const int e0 = ptr[gid], e1 = ptr[gid + 1];
  float d = dis[gid];
  float ss = d * d;
  float4 acc = *reinterpret_cast<const float4*>(h + (size_t)gid * F + lane * 4);
  acc.x *= ss; acc.y *= ss; acc.z *= ss; acc.w *= ss;
  int e = e0;
  for (; e + 4 <= e1; e += 4) {
    int2 d0 = edat[e], d1 = edat[e + 1], d2 = edat[e + 2], d3 = edat[e + 3];
    float4 v0 = *reinterpret_cast<const float4*>(h + (size_t)d0.x * F + lane * 4);
    float4 v1 = *reinterpret_cast<const float4*>(h + (size_t)d1.x * F + lane * 4);
    float4 v2 = *reinterpret_cast<const float4*>(h + (size_t)d2.x * F + lane * 4);
    float4 v3 = *reinterpret_cast<const float4*>(h + (size_t)d3.x * F + lane * 4);
    float n0 = __int_as_float(d0.y), n1 = __int_as_float(d1.y);
    float n2 = __int_as_float(d2.y), n3 = __int_as_float(d3.y);
    acc.x += n0 * v0.x; acc.y += n0 * v0.y; acc.z += n0 * v0.z; acc.w += n0 * v0.w;
    acc.x += n1 * v1.x; acc.y += n1 * v1.y; acc.z += n1 * v1.z; acc.w += n1 * v1.w;
    acc.x += n2 * v2.x; acc.y += n2 * v2.y; acc.z += n2 * v2.z; acc.w += n2 * v2.w;
    acc.x += n3 * v3.x; acc.y += n3 * v3.y; acc.z += n3 * v3.z; acc.w += n3 * v3.w;
  }
  for (; e < e1; ++e) {
    int2 ed = edat[e];
    float nv = __int_as_float(ed.y);
    float4 v = *reinterpret_cast<const float4*>(h + (size_t)ed.x * F + lane * 4);
    acc.x += nv * v.x; acc.y += nv * v.y; acc.z += nv * v.z; acc.w += nv * v.w;
  }
  if (BIAS) {
    float4 bb = *reinterpret_cast<const float4*>(bias + lane * 4);
    acc.x += bb.x; acc.y += bb.y; acc.z += bb.z; acc.w += bb.w;
  }
  if (RELU) {
    acc.x = fmaxf(acc.x, 0.f); acc.y = fmaxf(acc.y, 0.f);
    acc.z = fmaxf(acc.z, 0.f); acc.w = fmaxf(acc.w, 0.f);
  }
  if (OUTP) {
    ushort4 hv, lv;
    hv.x = f2bf(acc.x); lv.x = f2bf(acc.x - bf2f(hv.x));
    hv.y = f2bf(acc.y); lv.y = f2bf(acc.y - bf2f(hv.y));
    hv.z = f2bf(acc.z); lv.z = f2bf(acc.z - bf2f(hv.z));
    hv.w = f2bf(acc.w); lv.w = f2bf(acc.w - bf2f(hv.w));
    *reinterpret_cast<ushort4*>(ohi + (size_t)gid * F + lane * 4) = hv;
    *reinterpret_cast<ushort4*>(olo + (size_t)gid * F + lane * 4) = lv;
  } else {
    *reinterpret_cast<float4*>(outf + (size_t)gid * F + lane * 4) = acc;
  }
}

// Layer-3 aggregation (F=64) into padded [ng, npg+1, 64] output, +b3. 4x unrolled.
__global__ __launch_bounds__(256) void k_gagg_out(const int* __restrict__ ptr,
                                                  const int2* __restrict__ edat,
                                                  const float* __restrict__ t3,
                                                  const float* __restrict__ dis,
                                                  const float* __restrict__ b3,
                                                  float* __restrict__ out,
                                                  const int* __restrict__ ngp,
                                                  int n, int nrows) {
  const int gid = blockIdx.x * 16 + threadIdx.x / 16;
  const int lane = threadIdx.x % 16;
  if (gid >= nrows) return;
  const int ng = *ngp;
  const int npg = n / ng;
  const int g = gid / (npg + 1);
  const int r = gid - g * (npg + 1);
  float4 acc = make_float4(0.f, 0.f, 0.f, 0.f);
  if (r < npg) {
    const int i = g * npg + r;
    const int e0 = ptr[i], e1 = ptr[i + 1];
    float d = dis[i];
    float ss = d * d;
    acc = *reinterpret_cast<const float4*>(t3 + (size_t)i * 64 + lane * 4);
    acc.x *= ss; acc.y *= ss; acc.z *= ss; acc.w *= ss;
    int e = e0;
    for (; e + 4 <= e1; e += 4) {
      int2 d0 = edat[e], d1 = edat[e + 1], d2 = edat[e + 2], d3 = edat[e + 3];
      float4 v0 = *reinterpret_cast<const float4*>(t3 + (size_t)d0.x * 64 + lane * 4);
      float4 v1 = *reinterpret_cast<const float4*>(t3 + (size_t)d1.x * 64 + lane * 4);
      float4 v2 = *reinterpret_cast<const float4*>(t3 + (size_t)d2.x * 64 + lane * 4);
      float4 v3 = *reinterpret_cast<const float4*>(t3 + (size_t)d3.x * 64 + lane * 4);
      float n0 = __int_as_float(d0.y), n1 = __int_as_float(d1.y);
      float n2 = __int_as_float(d2.y), n3 = __int_as_float(d3.y);
      acc.x += n0 * v0.x; acc.y += n0 * v0.y; acc.z += n0 * v0.z; acc.w += n0 * v0.w;
      acc.x += n1 * v1.x; acc.y += n1 * v1.y; acc.z += n1 * v1.z; acc.w += n1 * v1.w;
      acc.x += n2 * v2.x; acc.y += n2 * v2.y; acc.z += n2 * v2.z; acc.w += n2 * v2.w;
      acc.x += n3 * v3.x; acc.y += n3 * v3.y; acc.z += n3 * v3.z; acc.w += n3 * v3.w;
    }
    for (; e < e1; ++e) {
      int2 ed = edat[e];
      float nv = __int_as_float(ed.y);
      float4 v = *reinterpret_cast<const float4*>(t3 + (size_t)ed.x * 64 + lane * 4);
      acc.x += nv * v.x; acc.y += nv * v.y; acc.z += nv * v.z; acc.w += nv * v.w;
    }
    float4 bb = *reinterpret_cast<const float4*>(b3 + lane * 4);
    acc.x += bb.x; acc.y += bb.y; acc.z += bb.z; acc.w += bb.w;
  }
  *reinterpret_cast<float4*>(out + (size_t)gid * 64 + lane * 4) = acc;
}

// ================= split-bf16 MFMA GEMM =================
// C[N,M] = A[N,K]*B[K,M], A given as hi/lo bf16 planes (row-major), B as
// frag-ordered hi/lo bf16. BM=128, BN=64, 256 threads (4 waves, each 64x32).
// A*B ~= Ah*Bh + Ah*Bl + Al*Bh via mfma_f32_16x16x32_bf16 (f32 accumulate).

template<bool BIAS, bool RELU, bool OUTP>
__global__ __launch_bounds__(256) void gemm_mfma(
    const unsigned short* __restrict__ Ahi, const unsigned short* __restrict__ Alo,
    const unsigned short* __restrict__ BfHi, const unsigned short* __restrict__ BfLo,
    const float* __restrict__ bias,
    float* __restrict__ Cf, unsigned short* __restrict__ Chi,
    unsigned short* __restrict__ Clo, int K, int M) {
  __shared__ unsigned short AL[2][4096];  // [plane][512 slots * 8 bf16] = 8KB each
  const int tid = threadIdx.x;
  const int l = tid & 63;
  const int w = tid >> 6;
  const int m0 = blockIdx.x * 128;
  const int wmt = (w >> 1) * 4;      // wave's first m-tile (of 8)
  const int wn = (w & 1) * 2;        // wave's first n-tile within block (of 4)
  const int ntile0 = blockIdx.y * 4 + wn;
  const int nt16 = M >> 4;

  f32x4 acc[4][2];
#pragma unroll
  for (int a = 0; a < 4; ++a)
#pragma unroll
    for (int b = 0; b < 2; ++b) acc[a][b] = f32x4{0.f, 0.f, 0.f, 0.f};

  const int nks = K >> 5;
  for (int ks = 0; ks < nks; ++ks) {
    if (ks) __syncthreads();
    // stage A tile (128 rows x 32 k), frag-ordered LDS: slot = mt*64 + lane
#pragma unroll
    for (int rr = 0; rr < 2; ++rr) {
      int s = rr * 256 + tid;
      int mt = s >> 6, sl = s & 63;
      size_t grow = (size_t)(m0 + mt * 16 + (sl & 15)) * K + (ks << 5) + ((sl >> 4) << 3);
      gload_lds16(Ahi + grow, &AL[0][(size_t)s * 8]);
      gload_lds16(Alo + grow, &AL[1][(size_t)s * 8]);
    }
    // B frags from global (L1/L2 hot)
    int4 braw[2][2];
#pragma unroll
    for (int nt = 0; nt < 2; ++nt) {
      size_t bidx = ((size_t)(ks * nt16 + ntile0 + nt) * 64 + l) * 8;
      braw[nt][0] = *reinterpret_cast<const int4*>(BfHi + bidx);
      braw[nt][1] = *reinterpret_cast<const int4*>(BfLo + bidx);
    }
    asm volatile("s_waitcnt vmcnt(0)" ::: "memory");
    __syncthreads();
#pragma unroll
    for (int mt = 0; mt < 4; ++mt) {
      int slot = (wmt + mt) * 64 + l;
      bf16x8 ah = __builtin_bit_cast(bf16x8, *reinterpret_cast<const int4*>(&AL[0][(size_t)slot * 8]));
      bf16x8 al = __builtin_bit_cast(bf16x8, *reinterpret_cast<const int4*>(&AL[1][(size_t)slot * 8]));
#pragma unroll
      for (int nt = 0; nt < 2; ++nt) {
        bf16x8 bh = __builtin_bit_cast(bf16x8, braw[nt][0]);
        bf16x8 bl = __builtin_bit_cast(bf16x8, braw[nt][1]);
        acc[mt][nt] = __builtin_amdgcn_mfma_f32_16x16x32_bf16(al, bh, acc[mt][nt], 0, 0, 0);
        acc[mt][nt] = __builtin_amdgcn_mfma_f32_16x16x32_bf16(ah, bl, acc[mt][nt], 0, 0, 0);
        acc[mt][nt] = __builtin_amdgcn_mfma_f32_16x16x32_bf16(ah, bh, acc[mt][nt], 0, 0, 0);
      }
    }
  }
  // epilogue: D row = (l>>4)*4 + i, col = l&15
#pragma unroll
  for (int mt = 0; mt < 4; ++mt) {
    int rowb = m0 + (wmt + mt) * 16 + ((l >> 4) << 2);
#pragma unroll
    for (int nt = 0; nt < 2; ++nt) {
      int colg = (ntile0 + nt) * 16 + (l & 15);
      float bv = 0.f;
      if (BIAS) bv = bias[colg];
#pragma unroll
      for (int i = 0; i < 4; ++i) {
        float v = acc[mt][nt][i] + bv;
        if (RELU) v = fmaxf(v, 0.f);
        size_t off = (size_t)(rowb + i) * M + colg;
        if (OUTP) {
          unsigned short hh = f2bf(v);
          Chi[off] = hh;
          Clo[off] = f2bf(v - bf2f(hh));
        } else {
          Cf[off] = v;
        }
      }
    }
  }
}

// ================= launch =================

static inline int nblk(long work, int tpb = TPB) { return (int)((work + tpb - 1) / tpb); }

extern "C" void kernel_launch(void* const* d_in, const int* in_sizes, int n_in,
                              void* d_out, int out_size, void* d_ws, size_t ws_size,
                              hipStream_t stream) {
  const float* x  = (const float*)d_in[0];
  const int*   ei = (const int*)d_in[1];
  const float* ew = (const float*)d_in[2];
  const int*  ngp = (const int*)d_in[3];
  const float* W1 = (const float*)d_in[4];
  const float* b1 = (const float*)d_in[5];
  const float* W2 = (const float*)d_in[6];
  const float* b2 = (const float*)d_in[7];
  const float* W3 = (const float*)d_in[8];
  const float* b3 = (const float*)d_in[9];
  float* out = (float*)d_out;

  const int n = in_sizes[0] / 128;  // 65536
  const int E = in_sizes[2];        // 1048576
  const int* row = ei;
  const int* col = ei + E;

  const size_t MB = 1024 * 1024;
  char* W8 = (char*)d_ws;
  int2* edat = (int2*)W8;                        // 8 MB
  int* cnt   = (int*)(W8 + 8 * MB);              // n
  int* ptrv  = cnt + n;                          // n+1
  int* cur   = ptrv + n + 1;                     // n
  int* bsum  = cur + n;                          // 256
  int* boff  = bsum + 256;                       // 256
  float* dis = (float*)(boff + 256);             // n
  // region A (16..50 MB): t1 planes -> t2 f32 -> t3 f32 (sequentially dead)
  unsigned short* t1hi = (unsigned short*)(W8 + 16 * MB);  // 16 MB
  unsigned short* t1lo = (unsigned short*)(W8 + 32 * MB);  // 16 MB
  float* t2 = (float*)(W8 + 16 * MB);                      // 32 MB (alias t1)
  float* t3 = (float*)(W8 + 16 * MB);                      // 16 MB (alias t2)
  // region B (56..120 MB): h1 planes -> h2 planes
  unsigned short* h1hi = (unsigned short*)(W8 + 56 * MB);  // 32 MB
  unsigned short* h1lo = (unsigned short*)(W8 + 88 * MB);  // 32 MB
  unsigned short* h2hi = (unsigned short*)(W8 + 56 * MB);  // 16 MB (alias h1)
  unsigned short* h2lo = (unsigned short*)(W8 + 72 * MB);  // 16 MB
  // W fragments (120 MB..)
  unsigned short* w1fh = (unsigned short*)(W8 + 120 * MB);
  unsigned short* w1fl = w1fh + 32768;
  unsigned short* w2fh = w1fl + 32768;
  unsigned short* w2fl = w2fh + 32768;
  unsigned short* w3fh = w2fl + 32768;
  unsigned short* w3fl = w3fh + 8192;

  // ---- CSR build + norms
  k_init<<<nblk(n), TPB, 0, stream>>>(cnt, dis, n);
  k_count_deg<<<nblk(E), TPB, 0, stream>>>(col, ew, cnt, dis, E);
  k_rsqrt<<<nblk(n), TPB, 0, stream>>>(dis, n);
  k_reduceA<<<n / 256, 256, 0, stream>>>(cnt, bsum);
  k_scanB<<<1, 256, 0, stream>>>(bsum, boff);
  k_scanC<<<n / 256, 256, 0, stream>>>(cnt, boff, ptrv, cur, n);
  k_scatter_norm<<<nblk(E), TPB, 0, stream>>>(row, col, ew, dis, cur, edat, E);

  // ---- weight fragment prep
  k_wprep<<<nblk(128 * 256 / 8), TPB, 0, stream>>>(W1, w1fh, w1fl, 128, 256);
  k_wprep<<<nblk(256 * 128 / 8), TPB, 0, stream>>>(W2, w2fh, w2fl, 256, 128);
  k_wprep<<<nblk(128 * 64 / 8), TPB, 0, stream>>>(W3, w3fh, w3fl, 128, 64);

  // ---- layer 1: t1 = A(x) (hi/lo planes); h1 = relu(t1@W1+b1) (hi/lo planes)
  k_gagg<32, false, false, true><<<nblk((long)n * 32), TPB, 0, stream>>>(
      ptrv, edat, x, dis, nullptr, nullptr, t1hi, t1lo, n);
  {
    dim3 g(n / 128, 256 / 64);
    gemm_mfma<true, true, true><<<g, 256, 0, stream>>>(
        t1hi, t1lo, w1fh, w1fl, b1, nullptr, h1hi, h1lo, 128, 256);
  }

  // ---- layer 2: t2 = h1@W2 (f32); h2 = relu(A(t2)+b2) (hi/lo planes)
  {
    dim3 g(n / 128, 128 / 64);
    gemm_mfma<false, false, false><<<g, 256, 0, stream>>>(
        h1hi, h1lo, w2fh, w2fl, nullptr, t2, nullptr, nullptr, 256, 128);
  }
  k_gagg<32, true, true, true><<<nblk((long)n * 32), TPB, 0, stream>>>(
      ptrv, edat, t2, dis, b2, nullptr, h2hi, h2lo, n);

  // ---- layer 3: t3 = h2@W3 (f32); out = A(t3)+b3 into padded layout
  {
    dim3 g(n / 128, 64 / 64);
    gemm_mfma<false, false, false><<<g, 256, 0, stream>>>(
        h2hi, h2lo, w3fh, w3fl, nullptr, t3, nullptr, nullptr, 128, 64);
  }
  const int nrows = out_size / 64;
  k_gagg_out<<<nblk((long)nrows * 16), TPB, 0, stream>>>(
      ptrv, edat, t3, dis, b3, out, ngp, n, nrows);
}

// Round 6
// 469.649 us; speedup vs baseline: 10.0672x; 1.1183x over previous
//
#include <hip/hip_runtime.h>
#include <cstdint>

#define TPB 256

typedef __attribute__((ext_vector_type(8))) short bf16x8;
typedef __attribute__((ext_vector_type(4))) float f32x4;

__device__ inline unsigned short f2bf(float f) {
  unsigned u = __float_as_uint(f);
  u += 0x7fffu + ((u >> 16) & 1u);
  return (unsigned short)(u >> 16);
}
__device__ inline float bf2f(unsigned short h) {
  return __uint_as_float(((unsigned)h) << 16);
}

__device__ inline void gload_lds16(const void* g, void* l) {
  __builtin_amdgcn_global_load_lds(
      (const __attribute__((address_space(1))) unsigned int*)g,
      (__attribute__((address_space(3))) unsigned int*)l, 16, 0, 0);
}

// ================= packed count+deg (one u64 atomic per edge) =================
// pk[c] += (1<<40) | round(w * 2^32).  count = pk>>40; degsum = low40 * 2^-32.

__global__ void k_count_deg(const int* __restrict__ col, const float* __restrict__ w,
                            unsigned long long* __restrict__ pk, int E) {
  int e = blockIdx.x * blockDim.x + threadIdx.x;
  if (e >= E) return;
  int c = col[e];
  unsigned long long inc =
      (1ULL << 40) + (unsigned long long)(unsigned int)(w[e] * 4294967296.0f);
  atomicAdd(&pk[c], inc);
}

__global__ void k_decode(const unsigned long long* __restrict__ pk, float* __restrict__ dis,
                         int* __restrict__ cnt, int n) {
  int i = blockIdx.x * blockDim.x + threadIdx.x;
  if (i >= n) return;
  unsigned long long v = pk[i];
  cnt[i] = (int)(v >> 40);
  float degs = (float)(v & 0xFFFFFFFFFFULL) * 2.3283064365386963e-10f;  // 2^-32
  dis[i] = rsqrtf(1.0f + degs);
}

// ================= parallel scan =================

__global__ void k_reduceA(const int* __restrict__ cnt, int* __restrict__ bsum) {
  __shared__ int s[256];
  int t = threadIdx.x;
  s[t] = cnt[blockIdx.x * 256 + t];
  __syncthreads();
  for (int st = 128; st > 0; st >>= 1) {
    if (t < st) s[t] += s[t + st];
    __syncthreads();
  }
  if (t == 0) bsum[blockIdx.x] = s[0];
}

__global__ void k_scanB(const int* __restrict__ bsum, int* __restrict__ boff) {
  __shared__ int s[256];
  int t = threadIdx.x;
  int v = bsum[t];
  s[t] = v;
  __syncthreads();
  for (int st = 1; st < 256; st <<= 1) {
    int a = (t >= st) ? s[t - st] : 0;
    __syncthreads();
    s[t] += a;
    __syncthreads();
  }
  boff[t] = s[t] - v;
}

__global__ void k_scanC(const int* __restrict__ cnt, const int* __restrict__ boff,
                        int* __restrict__ ptr, int* __restrict__ cur, int n) {
  __shared__ int s[256];
  int t = threadIdx.x;
  int i = blockIdx.x * 256 + t;
  int v = cnt[i];
  s[t] = v;
  __syncthreads();
  for (int st = 1; st < 256; st <<= 1) {
    int a = (t >= st) ? s[t - st] : 0;
    __syncthreads();
    s[t] += a;
    __syncthreads();
  }
  int excl = boff[blockIdx.x] + s[t] - v;
  ptr[i] = excl;
  cur[i] = excl;
  if (i == n - 1) ptr[n] = excl + v;
}

// ================= scatter with fused norm =================

__global__ void k_scatter_norm(const int* __restrict__ row, const int* __restrict__ col,
                               const float* __restrict__ w, const float* __restrict__ dis,
                               int* __restrict__ cur, int2* __restrict__ edat, int E) {
  int e = blockIdx.x * blockDim.x + threadIdx.x;
  if (e >= E) return;
  int c = col[e];
  int r = row[e];
  float nv = dis[r] * w[e] * dis[c];
  int p = atomicAdd(&cur[c], 1);
  edat[p] = make_int2(r, __float_as_int(nv));
}

// ================= fused W fragment prep (all three weights) =================
// Bfrag layout: idx = ((ks*(M/16) + c0t)*64 + lane)*8 + j
// value = W[ks*32 + (lane>>4)*8 + j][c0t*16 + (lane&15)]  split into hi/lo bf16.

__device__ inline void wprep_one(const float* __restrict__ W, unsigned short* __restrict__ Fh,
                                 unsigned short* __restrict__ Fl, int t, int M) {
  int l = t & 63;
  int rest = t >> 6;
  int nt16 = M >> 4;
  int c0t = rest % nt16;
  int ks = rest / nt16;
  int colg = c0t * 16 + (l & 15);
  int krow = (ks << 5) + ((l >> 4) << 3);
  size_t ob = (size_t)t * 8;
#pragma unroll
  for (int j = 0; j < 8; ++j) {
    float f = W[(size_t)(krow + j) * M + colg];
    unsigned short h = f2bf(f);
    Fh[ob + j] = h;
    Fl[ob + j] = f2bf(f - bf2f(h));
  }
}

__global__ void k_wprep3(const float* __restrict__ W1, const float* __restrict__ W2,
                         const float* __restrict__ W3,
                         unsigned short* __restrict__ f1h, unsigned short* __restrict__ f1l,
                         unsigned short* __restrict__ f2h, unsigned short* __restrict__ f2l,
                         unsigned short* __restrict__ f3h, unsigned short* __restrict__ f3l) {
  int t = blockIdx.x * blockDim.x + threadIdx.x;
  if (t < 4096) wprep_one(W1, f1h, f1l, t, 256);            // 128x256: (128/32)*(256/16)*64
  else if (t < 8192) wprep_one(W2, f2h, f2l, t - 4096, 128);  // 256x128
  else if (t < 9216) wprep_one(W3, f3h, f3l, t - 8192, 64);   // 128x64
}

// ================= gather aggregation (8/4/1 unroll ladder) =================

template<int GL, bool RELU, bool BIAS, bool OUTP>
__global__ __launch_bounds__(256) void k_gagg(const int* __restrict__ ptr,
                                              const int2* __restrict__ edat,
                                              const float* __restrict__ h,
                                              const float* __restrict__ dis,
                                              const float* __restrict__ bias,
                                              float* __restrict__ outf,
                                              unsigned short* __restrict__ ohi,
                                              unsigned short* __restrict__ olo, int n) {
  constexpr int GPB = 256 / GL;
  const int gid = blockIdx.x * GPB + threadIdx.x / GL;
  const int lane = threadIdx.x % GL;
  if (gid >= n) return;
  constexpr int F = GL * 4;
  const int e0 = ptr[gid], e1 = ptr[gid + 1];
  float d = dis[gid];
  float ss = d * d;
  float4 acc = *reinterpret_cast<const float4*>(h + (size_t)gid * F + lane * 4);
  acc.x *= ss; acc.y *= ss; acc.z *= ss; acc.w *= ss;
  int e = e0;
  for (; e + 8 <= e1; e += 8) {
    int2 ed[8];
#pragma unroll
    for (int u = 0; u < 8; ++u) ed[u] = edat[e + u];
    float4 v[8];
#pragma unroll
    for (int u = 0; u < 8; ++u)
      v[u] = *reinterpret_cast<const float4*>(h + (size_t)ed[u].x * F + lane * 4);
#pragma unroll
    for (int u = 0; u < 8; ++u) {
      float nv = __int_as_float(ed[u].y);
      acc.x += nv * v[u].x; acc.y += nv * v[u].y;
      acc.z += nv * v[u].z; acc.w += nv * v[u].w;
    }
  }
  for (; e + 4 <= e1; e += 4) {
    int2 ed[4];
#pragma unroll
    for (int u = 0; u < 4; ++u) ed[u] = edat[e + u];
    float4 v[4];
#pragma unroll
    for (int u = 0; u < 4; ++u)
      v[u] = *reinterpret_cast<const float4*>(h + (size_t)ed[u].x * F + lane * 4);
#pragma unroll
    for (int u = 0; u < 4; ++u) {
      float nv = __int_as_float(ed[u].y);
      acc.x += nv * v[u].x; acc.y += nv * v[u].y;
      acc.z += nv * v[u].z; acc.w += nv * v[u].w;
    }
  }
  for (; e < e1; ++e) {
    int2 ed = edat[e];
    float nv = __int_as_float(ed.y);
    float4 v = *reinterpret_cast<const float4*>(h + (size_t)ed.x * F + lane * 4);
    acc.x += nv * v.x; acc.y += nv * v.y; acc.z += nv * v.z; acc.w += nv * v.w;
  }
  if (BIAS) {
    float4 bb = *reinterpret_cast<const float4*>(bias + lane * 4);
    acc.x += bb.x; acc.y += bb.y; acc.z += bb.z; acc.w += bb.w;
  }
  if (RELU) {
    acc.x = fmaxf(acc.x, 0.f); acc.y = fmaxf(acc.y, 0.f);
    acc.z = fmaxf(acc.z, 0.f); acc.w = fmaxf(acc.w, 0.f);
  }
  if (OUTP) {
    ushort4 hv, lv;
    hv.x = f2bf(acc.x); lv.x = f2bf(acc.x - bf2f(hv.x));
    hv.y = f2bf(acc.y); lv.y = f2bf(acc.y - bf2f(hv.y));
    hv.z = f2bf(acc.z); lv.z = f2bf(acc.z - bf2f(hv.z));
    hv.w = f2bf(acc.w); lv.w = f2bf(acc.w - bf2f(hv.w));
    *reinterpret_cast<ushort4*>(ohi + (size_t)gid * F + lane * 4) = hv;
    *reinterpret_cast<ushort4*>(olo + (size_t)gid * F + lane * 4) = lv;
  } else {
    *reinterpret_cast<float4*>(outf + (size_t)gid * F + lane * 4) = acc;
  }
}

// Layer-3 aggregation (F=64) into padded [ng, npg+1, 64] output, +b3.
__global__ __launch_bounds__(256) void k_gagg_out(const int* __restrict__ ptr,
                                                  const int2* __restrict__ edat,
                                                  const float* __restrict__ t3,
                                                  const float* __restrict__ dis,
                                                  const float* __restrict__ b3,
                                                  float* __restrict__ out,
                                                  const int* __restrict__ ngp,
                                                  int n, int nrows) {
  const int gid = blockIdx.x * 16 + threadIdx.x / 16;
  const int lane = threadIdx.x % 16;
  if (gid >= nrows) return;
  const int ng = *ngp;
  const int npg = n / ng;
  const int g = gid / (npg + 1);
  const int r = gid - g * (npg + 1);
  float4 acc = make_float4(0.f, 0.f, 0.f, 0.f);
  if (r < npg) {
    const int i = g * npg + r;
    const int e0 = ptr[i], e1 = ptr[i + 1];
    float d = dis[i];
    float ss = d * d;
    acc = *reinterpret_cast<const float4*>(t3 + (size_t)i * 64 + lane * 4);
    acc.x *= ss; acc.y *= ss; acc.z *= ss; acc.w *= ss;
    int e = e0;
    for (; e + 8 <= e1; e += 8) {
      int2 ed[8];
#pragma unroll
      for (int u = 0; u < 8; ++u) ed[u] = edat[e + u];
      float4 v[8];
#pragma unroll
      for (int u = 0; u < 8; ++u)
        v[u] = *reinterpret_cast<const float4*>(t3 + (size_t)ed[u].x * 64 + lane * 4);
#pragma unroll
      for (int u = 0; u < 8; ++u) {
        float nv = __int_as_float(ed[u].y);
        acc.x += nv * v[u].x; acc.y += nv * v[u].y;
        acc.z += nv * v[u].z; acc.w += nv * v[u].w;
      }
    }
    for (; e + 4 <= e1; e += 4) {
      int2 ed[4];
#pragma unroll
      for (int u = 0; u < 4; ++u) ed[u] = edat[e + u];
      float4 v[4];
#pragma unroll
      for (int u = 0; u < 4; ++u)
        v[u] = *reinterpret_cast<const float4*>(t3 + (size_t)ed[u].x * 64 + lane * 4);
#pragma unroll
      for (int u = 0; u < 4; ++u) {
        float nv = __int_as_float(ed[u].y);
        acc.x += nv * v[u].x; acc.y += nv * v[u].y;
        acc.z += nv * v[u].z; acc.w += nv * v[u].w;
      }
    }
    for (; e < e1; ++e) {
      int2 ed = edat[e];
      float nv = __int_as_float(ed.y);
      float4 v = *reinterpret_cast<const float4*>(t3 + (size_t)ed.x * 64 + lane * 4);
      acc.x += nv * v.x; acc.y += nv * v.y; acc.z += nv * v.z; acc.w += nv * v.w;
    }
    float4 bb = *reinterpret_cast<const float4*>(b3 + lane * 4);
    acc.x += bb.x; acc.y += bb.y; acc.z += bb.z; acc.w += bb.w;
  }
  *reinterpret_cast<float4*>(out + (size_t)gid * 64 + lane * 4) = acc;
}

// ================= split-bf16 MFMA GEMM =================
// C[N,M] = A[N,K]*B[K,M]; A as hi/lo bf16 planes (row-major), B frag-ordered.
// BM=128, BN=64, 256 threads (4 waves). A*B ~= Al*Bh + Ah*Bl + Ah*Bh.

template<bool BIAS, bool RELU, bool OUTP>
__global__ __launch_bounds__(256) void gemm_mfma(
    const unsigned short* __restrict__ Ahi, const unsigned short* __restrict__ Alo,
    const unsigned short* __restrict__ BfHi, const unsigned short* __restrict__ BfLo,
    const float* __restrict__ bias,
    float* __restrict__ Cf, unsigned short* __restrict__ Chi,
    unsigned short* __restrict__ Clo, int K, int M) {
  __shared__ unsigned short AL[2][4096];
  const int tid = threadIdx.x;
  const int l = tid & 63;
  const int w = tid >> 6;
  const int m0 = blockIdx.x * 128;
  const int wmt = (w >> 1) * 4;
  const int wn = (w & 1) * 2;
  const int ntile0 = blockIdx.y * 4 + wn;
  const int nt16 = M >> 4;

  f32x4 acc[4][2];
#pragma unroll
  for (int a = 0; a < 4; ++a)
#pragma unroll
    for (int b = 0; b < 2; ++b) acc[a][b] = f32x4{0.f, 0.f, 0.f, 0.f};

  const int nks = K >> 5;
  for (int ks = 0; ks < nks; ++ks) {
    if (ks) __syncthreads();
#pragma unroll
    for (int rr = 0; rr < 2; ++rr) {
      int s = rr * 256 + tid;
      int mt = s >> 6, sl = s & 63;
      size_t grow = (size_t)(m0 + mt * 16 + (sl & 15)) * K + (ks << 5) + ((sl >> 4) << 3);
      gload_lds16(Ahi + grow, &AL[0][(size_t)s * 8]);
      gload_lds16(Alo + grow, &AL[1][(size_t)s * 8]);
    }
    int4 braw[2][2];
#pragma unroll
    for (int nt = 0; nt < 2; ++nt) {
      size_t bidx = ((size_t)(ks * nt16 + ntile0 + nt) * 64 + l) * 8;
      braw[nt][0] = *reinterpret_cast<const int4*>(BfHi + bidx);
      braw[nt][1] = *reinterpret_cast<const int4*>(BfLo + bidx);
    }
    asm volatile("s_waitcnt vmcnt(0)" ::: "memory");
    __syncthreads();
#pragma unroll
    for (int mt = 0; mt < 4; ++mt) {
      int slot = (wmt + mt) * 64 + l;
      bf16x8 ah = __builtin_bit_cast(bf16x8, *reinterpret_cast<const int4*>(&AL[0][(size_t)slot * 8]));
      bf16x8 al = __builtin_bit_cast(bf16x8, *reinterpret_cast<const int4*>(&AL[1][(size_t)slot * 8]));
#pragma unroll
      for (int nt = 0; nt < 2; ++nt) {
        bf16x8 bh = __builtin_bit_cast(bf16x8, braw[nt][0]);
        bf16x8 bl = __builtin_bit_cast(bf16x8, braw[nt][1]);
        acc[mt][nt] = __builtin_amdgcn_mfma_f32_16x16x32_bf16(al, bh, acc[mt][nt], 0, 0, 0);
        acc[mt][nt] = __builtin_amdgcn_mfma_f32_16x16x32_bf16(ah, bl, acc[mt][nt], 0, 0, 0);
        acc[mt][nt] = __builtin_amdgcn_mfma_f32_16x16x32_bf16(ah, bh, acc[mt][nt], 0, 0, 0);
      }
    }
  }
#pragma unroll
  for (int mt = 0; mt < 4; ++mt) {
    int rowb = m0 + (wmt + mt) * 16 + ((l >> 4) << 2);
#pragma unroll
    for (int nt = 0; nt < 2; ++nt) {
      int colg = (ntile0 + nt) * 16 + (l & 15);
      float bv = 0.f;
      if (BIAS) bv = bias[colg];
#pragma unroll
      for (int i = 0; i < 4; ++i) {
        float v = acc[mt][nt][i] + bv;
        if (RELU) v = fmaxf(v, 0.f);
        size_t off = (size_t)(rowb + i) * M + colg;
        if (OUTP) {
          unsigned short hh = f2bf(v);
          Chi[off] = hh;
          Clo[off] = f2bf(v - bf2f(hh));
        } else {
          Cf[off] = v;
        }
      }
    }
  }
}

// ================= launch =================

static inline int nblk(long work, int tpb = TPB) { return (int)((work + tpb - 1) / tpb); }

extern "C" void kernel_launch(void* const* d_in, const int* in_sizes, int n_in,
                              void* d_out, int out_size, void* d_ws, size_t ws_size,
                              hipStream_t stream) {
  const float* x  = (const float*)d_in[0];
  const int*   ei = (const int*)d_in[1];
  const float* ew = (const float*)d_in[2];
  const int*  ngp = (const int*)d_in[3];
  const float* W1 = (const float*)d_in[4];
  const float* b1 = (const float*)d_in[5];
  const float* W2 = (const float*)d_in[6];
  const float* b2 = (const float*)d_in[7];
  const float* W3 = (const float*)d_in[8];
  const float* b3 = (const float*)d_in[9];
  float* out = (float*)d_out;

  const int n = in_sizes[0] / 128;  // 65536
  const int E = in_sizes[2];        // 1048576
  const int* row = ei;
  const int* col = ei + E;

  const size_t MB = 1024 * 1024;
  char* W8 = (char*)d_ws;
  int2* edat = (int2*)W8;                                  // 8 MB
  unsigned long long* pk = (unsigned long long*)(W8 + 8 * MB);  // n u64
  int* cnt   = (int*)(pk + n);                             // n
  int* ptrv  = cnt + n;                                    // n+1
  int* cur   = ptrv + n + 1;                               // n
  int* bsum  = cur + n;                                    // 256
  int* boff  = bsum + 256;                                 // 256
  float* dis = (float*)(boff + 256);                       // n
  // region A (16..48 MB): t1 planes -> t2 f32 -> t3 f32 (sequentially dead)
  unsigned short* t1hi = (unsigned short*)(W8 + 16 * MB);
  unsigned short* t1lo = (unsigned short*)(W8 + 32 * MB);
  float* t2 = (float*)(W8 + 16 * MB);
  float* t3 = (float*)(W8 + 16 * MB);
  // region B (56..120 MB): h1 planes -> h2 planes
  unsigned short* h1hi = (unsigned short*)(W8 + 56 * MB);
  unsigned short* h1lo = (unsigned short*)(W8 + 88 * MB);
  unsigned short* h2hi = (unsigned short*)(W8 + 56 * MB);
  unsigned short* h2lo = (unsigned short*)(W8 + 72 * MB);
  // W fragments (120 MB..)
  unsigned short* w1fh = (unsigned short*)(W8 + 120 * MB);
  unsigned short* w1fl = w1fh + 32768;
  unsigned short* w2fh = w1fl + 32768;
  unsigned short* w2fl = w2fh + 32768;
  unsigned short* w3fh = w2fl + 32768;
  unsigned short* w3fl = w3fh + 8192;

  // ---- CSR build + norms
  hipMemsetAsync(pk, 0, (size_t)n * 8, stream);
  k_count_deg<<<nblk(E), TPB, 0, stream>>>(col, ew, pk, E);
  k_decode<<<nblk(n), TPB, 0, stream>>>(pk, dis, cnt, n);
  k_reduceA<<<n / 256, 256, 0, stream>>>(cnt, bsum);
  k_scanB<<<1, 256, 0, stream>>>(bsum, boff);
  k_scanC<<<n / 256, 256, 0, stream>>>(cnt, boff, ptrv, cur, n);
  k_scatter_norm<<<nblk(E), TPB, 0, stream>>>(row, col, ew, dis, cur, edat, E);

  // ---- weight fragment prep (fused)
  k_wprep3<<<nblk(9216), TPB, 0, stream>>>(W1, W2, W3, w1fh, w1fl, w2fh, w2fl, w3fh, w3fl);

  // ---- layer 1
  k_gagg<32, false, false, true><<<nblk((long)n * 32), TPB, 0, stream>>>(
      ptrv, edat, x, dis, nullptr, nullptr, t1hi, t1lo, n);
  {
    dim3 g(n / 128, 256 / 64);
    gemm_mfma<true, true, true><<<g, 256, 0, stream>>>(
        t1hi, t1lo, w1fh, w1fl, b1, nullptr, h1hi, h1lo, 128, 256);
  }

  // ---- layer 2
  {
    dim3 g(n / 128, 128 / 64);
    gemm_mfma<false, false, false><<<g, 256, 0, stream>>>(
        h1hi, h1lo, w2fh, w2fl, nullptr, t2, nullptr, nullptr, 256, 128);
  }
  k_gagg<32, true, true, true><<<nblk((long)n * 32), TPB, 0, stream>>>(
      ptrv, edat, t2, dis, b2, nullptr, h2hi, h2lo, n);

  // ---- layer 3
  {
    dim3 g(n / 128, 64 / 64);
    gemm_mfma<false, false, false><<<g, 256, 0, stream>>>(
        h2hi, h2lo, w3fh, w3fl, nullptr, t3, nullptr, nullptr, 128, 64);
  }
  const int nrows = out_size / 64;
  k_gagg_out<<<nblk((long)nrows * 16), TPB, 0, stream>>>(
      ptrv, edat, t3, dis, b3, out, ngp, n, nrows);
}

// Round 7
// 425.287 us; speedup vs baseline: 11.1174x; 1.1043x over previous
//
#include <hip/hip_runtime.h>
#include <cstdint>

#define TPB 256

typedef __attribute__((ext_vector_type(8))) short bf16x8;
typedef __attribute__((ext_vector_type(4))) float f32x4;

__device__ inline unsigned short f2bf(float f) {
  unsigned u = __float_as_uint(f);
  u += 0x7fffu + ((u >> 16) & 1u);
  return (unsigned short)(u >> 16);
}
__device__ inline float bf2f(unsigned short h) {
  return __uint_as_float(((unsigned)h) << 16);
}

__device__ inline void gload_lds16(const void* g, void* l) {
  __builtin_amdgcn_global_load_lds(
      (const __attribute__((address_space(1))) unsigned int*)g,
      (__attribute__((address_space(3))) unsigned int*)l, 16, 0, 0);
}

// accumulate 8 bf16 features (packed in int4) scaled by nv into acc[0..7]
__device__ inline void acc_bf8(float* acc, int4 raw, float nv) {
  acc[0] += nv * __uint_as_float(((unsigned)raw.x) << 16);
  acc[1] += nv * __uint_as_float(((unsigned)raw.x) & 0xffff0000u);
  acc[2] += nv * __uint_as_float(((unsigned)raw.y) << 16);
  acc[3] += nv * __uint_as_float(((unsigned)raw.y) & 0xffff0000u);
  acc[4] += nv * __uint_as_float(((unsigned)raw.z) << 16);
  acc[5] += nv * __uint_as_float(((unsigned)raw.z) & 0xffff0000u);
  acc[6] += nv * __uint_as_float(((unsigned)raw.w) << 16);
  acc[7] += nv * __uint_as_float(((unsigned)raw.w) & 0xffff0000u);
}

// ================= packed count+deg (one u64 atomic per edge) =================

__global__ void k_count_deg(const int* __restrict__ col, const float* __restrict__ w,
                            unsigned long long* __restrict__ pk, int E) {
  int e = blockIdx.x * blockDim.x + threadIdx.x;
  if (e >= E) return;
  int c = col[e];
  unsigned long long inc =
      (1ULL << 40) + (unsigned long long)(unsigned int)(w[e] * 4294967296.0f);
  atomicAdd(&pk[c], inc);
}

__global__ void k_decode(const unsigned long long* __restrict__ pk, float* __restrict__ dis,
                         int* __restrict__ cnt, int n) {
  int i = blockIdx.x * blockDim.x + threadIdx.x;
  if (i >= n) return;
  unsigned long long v = pk[i];
  cnt[i] = (int)(v >> 40);
  float degs = (float)(v & 0xFFFFFFFFFFULL) * 2.3283064365386963e-10f;  // 2^-32
  dis[i] = rsqrtf(1.0f + degs);
}

// ================= parallel scan =================

__global__ void k_reduceA(const int* __restrict__ cnt, int* __restrict__ bsum) {
  __shared__ int s[256];
  int t = threadIdx.x;
  s[t] = cnt[blockIdx.x * 256 + t];
  __syncthreads();
  for (int st = 128; st > 0; st >>= 1) {
    if (t < st) s[t] += s[t + st];
    __syncthreads();
  }
  if (t == 0) bsum[blockIdx.x] = s[0];
}

__global__ void k_scanB(const int* __restrict__ bsum, int* __restrict__ boff) {
  __shared__ int s[256];
  int t = threadIdx.x;
  int v = bsum[t];
  s[t] = v;
  __syncthreads();
  for (int st = 1; st < 256; st <<= 1) {
    int a = (t >= st) ? s[t - st] : 0;
    __syncthreads();
    s[t] += a;
    __syncthreads();
  }
  boff[t] = s[t] - v;
}

__global__ void k_scanC(const int* __restrict__ cnt, const int* __restrict__ boff,
                        int* __restrict__ ptr, int* __restrict__ cur, int n) {
  __shared__ int s[256];
  int t = threadIdx.x;
  int i = blockIdx.x * 256 + t;
  int v = cnt[i];
  s[t] = v;
  __syncthreads();
  for (int st = 1; st < 256; st <<= 1) {
    int a = (t >= st) ? s[t - st] : 0;
    __syncthreads();
    s[t] += a;
    __syncthreads();
  }
  int excl = boff[blockIdx.x] + s[t] - v;
  ptr[i] = excl;
  cur[i] = excl;
  if (i == n - 1) ptr[n] = excl + v;
}

// ================= scatter with fused norm =================

__global__ void k_scatter_norm(const int* __restrict__ row, const int* __restrict__ col,
                               const float* __restrict__ w, const float* __restrict__ dis,
                               int* __restrict__ cur, int2* __restrict__ edat, int E) {
  int e = blockIdx.x * blockDim.x + threadIdx.x;
  if (e >= E) return;
  int c = col[e];
  int r = row[e];
  float nv = dis[r] * w[e] * dis[c];
  int p = atomicAdd(&cur[c], 1);
  edat[p] = make_int2(r, __float_as_int(nv));
}

// ================= fused W fragment prep (all three weights) =================

__device__ inline void wprep_one(const float* __restrict__ W, unsigned short* __restrict__ Fh,
                                 unsigned short* __restrict__ Fl, int t, int M) {
  int l = t & 63;
  int rest = t >> 6;
  int nt16 = M >> 4;
  int c0t = rest % nt16;
  int ks = rest / nt16;
  int colg = c0t * 16 + (l & 15);
  int krow = (ks << 5) + ((l >> 4) << 3);
  size_t ob = (size_t)t * 8;
#pragma unroll
  for (int j = 0; j < 8; ++j) {
    float f = W[(size_t)(krow + j) * M + colg];
    unsigned short h = f2bf(f);
    Fh[ob + j] = h;
    Fl[ob + j] = f2bf(f - bf2f(h));
  }
}

__global__ void k_wprep3(const float* __restrict__ W1, const float* __restrict__ W2,
                         const float* __restrict__ W3,
                         unsigned short* __restrict__ f1h, unsigned short* __restrict__ f1l,
                         unsigned short* __restrict__ f2h, unsigned short* __restrict__ f2l,
                         unsigned short* __restrict__ f3h, unsigned short* __restrict__ f3l) {
  int t = blockIdx.x * blockDim.x + threadIdx.x;
  if (t < 4096) wprep_one(W1, f1h, f1l, t, 256);
  else if (t < 8192) wprep_one(W2, f2h, f2l, t - 4096, 128);
  else if (t < 9216) wprep_one(W3, f3h, f3l, t - 8192, 64);
}

// ================= gather aggregation =================
// SRCBF=false: src f32, FPL=4 (float4/lane). SRCBF=true: src bf16, FPL=8 (ushort8/lane).
// Output: split hi/lo bf16 planes. out[i] = ss*src[i] + sum norm*src[row] (+bias, relu)

template<int GL, bool RELU, bool BIAS, bool SRCBF>
__global__ __launch_bounds__(256) void k_gagg(const int* __restrict__ ptr,
                                              const int2* __restrict__ edat,
                                              const void* __restrict__ srcv,
                                              const float* __restrict__ dis,
                                              const float* __restrict__ bias,
                                              unsigned short* __restrict__ ohi,
                                              unsigned short* __restrict__ olo, int n) {
  constexpr int FPL = SRCBF ? 8 : 4;
  constexpr int F = GL * FPL;
  constexpr int GPB = 256 / GL;
  const int gid = blockIdx.x * GPB + threadIdx.x / GL;
  const int lane = threadIdx.x % GL;
  if (gid >= n) return;
  const int e0 = ptr[gid], e1 = ptr[gid + 1];
  float d = dis[gid];
  float ss = d * d;
  float acc[FPL];
  const float* sF = (const float*)srcv;
  const unsigned short* sB = (const unsigned short*)srcv;
  if constexpr (SRCBF) {
    int4 raw = *reinterpret_cast<const int4*>(sB + (size_t)gid * F + lane * 8);
#pragma unroll
    for (int j = 0; j < 8; ++j) acc[j] = 0.f;
    acc_bf8(acc, raw, ss);
  } else {
    float4 v = *reinterpret_cast<const float4*>(sF + (size_t)gid * F + lane * 4);
    acc[0] = ss * v.x; acc[1] = ss * v.y; acc[2] = ss * v.z; acc[3] = ss * v.w;
  }
  int e = e0;
  for (; e + 8 <= e1; e += 8) {
    int2 ed[8];
#pragma unroll
    for (int u = 0; u < 8; ++u) ed[u] = edat[e + u];
    if constexpr (SRCBF) {
      int4 raw[8];
#pragma unroll
      for (int u = 0; u < 8; ++u)
        raw[u] = *reinterpret_cast<const int4*>(sB + (size_t)ed[u].x * F + lane * 8);
#pragma unroll
      for (int u = 0; u < 8; ++u) acc_bf8(acc, raw[u], __int_as_float(ed[u].y));
    } else {
      float4 v[8];
#pragma unroll
      for (int u = 0; u < 8; ++u)
        v[u] = *reinterpret_cast<const float4*>(sF + (size_t)ed[u].x * F + lane * 4);
#pragma unroll
      for (int u = 0; u < 8; ++u) {
        float nv = __int_as_float(ed[u].y);
        acc[0] += nv * v[u].x; acc[1] += nv * v[u].y;
        acc[2] += nv * v[u].z; acc[3] += nv * v[u].w;
      }
    }
  }
  for (; e + 4 <= e1; e += 4) {
    int2 ed[4];
#pragma unroll
    for (int u = 0; u < 4; ++u) ed[u] = edat[e + u];
    if constexpr (SRCBF) {
      int4 raw[4];
#pragma unroll
      for (int u = 0; u < 4; ++u)
        raw[u] = *reinterpret_cast<const int4*>(sB + (size_t)ed[u].x * F + lane * 8);
#pragma unroll
      for (int u = 0; u < 4; ++u) acc_bf8(acc, raw[u], __int_as_float(ed[u].y));
    } else {
      float4 v[4];
#pragma unroll
      for (int u = 0; u < 4; ++u)
        v[u] = *reinterpret_cast<const float4*>(sF + (size_t)ed[u].x * F + lane * 4);
#pragma unroll
      for (int u = 0; u < 4; ++u) {
        float nv = __int_as_float(ed[u].y);
        acc[0] += nv * v[u].x; acc[1] += nv * v[u].y;
        acc[2] += nv * v[u].z; acc[3] += nv * v[u].w;
      }
    }
  }
  for (; e < e1; ++e) {
    int2 ed = edat[e];
    float nv = __int_as_float(ed.y);
    if constexpr (SRCBF) {
      int4 raw = *reinterpret_cast<const int4*>(sB + (size_t)ed.x * F + lane * 8);
      acc_bf8(acc, raw, nv);
    } else {
      float4 v = *reinterpret_cast<const float4*>(sF + (size_t)ed.x * F + lane * 4);
      acc[0] += nv * v.x; acc[1] += nv * v.y; acc[2] += nv * v.z; acc[3] += nv * v.w;
    }
  }
  if (BIAS) {
#pragma unroll
    for (int j = 0; j < FPL; ++j) acc[j] += bias[lane * FPL + j];
  }
  if (RELU) {
#pragma unroll
    for (int j = 0; j < FPL; ++j) acc[j] = fmaxf(acc[j], 0.f);
  }
  unsigned short hv[FPL], lv[FPL];
#pragma unroll
  for (int j = 0; j < FPL; ++j) {
    hv[j] = f2bf(acc[j]);
    lv[j] = f2bf(acc[j] - bf2f(hv[j]));
  }
  if constexpr (FPL == 4) {
    *reinterpret_cast<ushort4*>(ohi + (size_t)gid * F + lane * 4) = *(ushort4*)hv;
    *reinterpret_cast<ushort4*>(olo + (size_t)gid * F + lane * 4) = *(ushort4*)lv;
  } else {
    *reinterpret_cast<int4*>(ohi + (size_t)gid * F + lane * 8) = *(int4*)hv;
    *reinterpret_cast<int4*>(olo + (size_t)gid * F + lane * 8) = *(int4*)lv;
  }
}

// Layer-3 aggregation: t3 bf16 [n,64] -> padded f32 out [ng, npg+1, 64], +b3.
// GL=8 lanes/row, 8 features (ushort8) per lane.
__global__ __launch_bounds__(256) void k_gagg_out(const int* __restrict__ ptr,
                                                  const int2* __restrict__ edat,
                                                  const unsigned short* __restrict__ t3,
                                                  const float* __restrict__ dis,
                                                  const float* __restrict__ b3,
                                                  float* __restrict__ out,
                                                  const int* __restrict__ ngp,
                                                  int n, int nrows) {
  const int gid = blockIdx.x * 32 + threadIdx.x / 8;
  const int lane = threadIdx.x % 8;
  if (gid >= nrows) return;
  const int ng = *ngp;
  const int npg = n / ng;
  const int g = gid / (npg + 1);
  const int r = gid - g * (npg + 1);
  float acc[8] = {0.f, 0.f, 0.f, 0.f, 0.f, 0.f, 0.f, 0.f};
  if (r < npg) {
    const int i = g * npg + r;
    const int e0 = ptr[i], e1 = ptr[i + 1];
    float d = dis[i];
    float ss = d * d;
    int4 sraw = *reinterpret_cast<const int4*>(t3 + (size_t)i * 64 + lane * 8);
    acc_bf8(acc, sraw, ss);
    int e = e0;
    for (; e + 8 <= e1; e += 8) {
      int2 ed[8];
#pragma unroll
      for (int u = 0; u < 8; ++u) ed[u] = edat[e + u];
      int4 raw[8];
#pragma unroll
      for (int u = 0; u < 8; ++u)
        raw[u] = *reinterpret_cast<const int4*>(t3 + (size_t)ed[u].x * 64 + lane * 8);
#pragma unroll
      for (int u = 0; u < 8; ++u) acc_bf8(acc, raw[u], __int_as_float(ed[u].y));
    }
    for (; e + 4 <= e1; e += 4) {
      int2 ed[4];
#pragma unroll
      for (int u = 0; u < 4; ++u) ed[u] = edat[e + u];
      int4 raw[4];
#pragma unroll
      for (int u = 0; u < 4; ++u)
        raw[u] = *reinterpret_cast<const int4*>(t3 + (size_t)ed[u].x * 64 + lane * 8);
#pragma unroll
      for (int u = 0; u < 4; ++u) acc_bf8(acc, raw[u], __int_as_float(ed[u].y));
    }
    for (; e < e1; ++e) {
      int2 ed = edat[e];
      int4 raw = *reinterpret_cast<const int4*>(t3 + (size_t)ed.x * 64 + lane * 8);
      acc_bf8(acc, raw, __int_as_float(ed.y));
    }
#pragma unroll
    for (int j = 0; j < 8; ++j) acc[j] += b3[lane * 8 + j];
  }
  float4 o0 = make_float4(acc[0], acc[1], acc[2], acc[3]);
  float4 o1 = make_float4(acc[4], acc[5], acc[6], acc[7]);
  *reinterpret_cast<float4*>(out + (size_t)gid * 64 + lane * 8) = o0;
  *reinterpret_cast<float4*>(out + (size_t)gid * 64 + lane * 8 + 4) = o1;
}

// ================= split-bf16 MFMA GEMM =================
// OUTM: 0 = f32, 1 = split hi/lo bf16 planes, 2 = single bf16 plane.

template<bool BIAS, bool RELU, int OUTM>
__global__ __launch_bounds__(256) void gemm_mfma(
    const unsigned short* __restrict__ Ahi, const unsigned short* __restrict__ Alo,
    const unsigned short* __restrict__ BfHi, const unsigned short* __restrict__ BfLo,
    const float* __restrict__ bias,
    float* __restrict__ Cf, unsigned short* __restrict__ Chi,
    unsigned short* __restrict__ Clo, int K, int M) {
  __shared__ unsigned short AL[2][4096];
  const int tid = threadIdx.x;
  const int l = tid & 63;
  const int w = tid >> 6;
  const int m0 = blockIdx.x * 128;
  const int wmt = (w >> 1) * 4;
  const int wn = (w & 1) * 2;
  const int ntile0 = blockIdx.y * 4 + wn;
  const int nt16 = M >> 4;

  f32x4 acc[4][2];
#pragma unroll
  for (int a = 0; a < 4; ++a)
#pragma unroll
    for (int b = 0; b < 2; ++b) acc[a][b] = f32x4{0.f, 0.f, 0.f, 0.f};

  const int nks = K >> 5;
  for (int ks = 0; ks < nks; ++ks) {
    if (ks) __syncthreads();
#pragma unroll
    for (int rr = 0; rr < 2; ++rr) {
      int s = rr * 256 + tid;
      int mt = s >> 6, sl = s & 63;
      size_t grow = (size_t)(m0 + mt * 16 + (sl & 15)) * K + (ks << 5) + ((sl >> 4) << 3);
      gload_lds16(Ahi + grow, &AL[0][(size_t)s * 8]);
      gload_lds16(Alo + grow, &AL[1][(size_t)s * 8]);
    }
    int4 braw[2][2];
#pragma unroll
    for (int nt = 0; nt < 2; ++nt) {
      size_t bidx = ((size_t)(ks * nt16 + ntile0 + nt) * 64 + l) * 8;
      braw[nt][0] = *reinterpret_cast<const int4*>(BfHi + bidx);
      braw[nt][1] = *reinterpret_cast<const int4*>(BfLo + bidx);
    }
    asm volatile("s_waitcnt vmcnt(0)" ::: "memory");
    __syncthreads();
#pragma unroll
    for (int mt = 0; mt < 4; ++mt) {
      int slot = (wmt + mt) * 64 + l;
      bf16x8 ah = __builtin_bit_cast(bf16x8, *reinterpret_cast<const int4*>(&AL[0][(size_t)slot * 8]));
      bf16x8 al = __builtin_bit_cast(bf16x8, *reinterpret_cast<const int4*>(&AL[1][(size_t)slot * 8]));
#pragma unroll
      for (int nt = 0; nt < 2; ++nt) {
        bf16x8 bh = __builtin_bit_cast(bf16x8, braw[nt][0]);
        bf16x8 bl = __builtin_bit_cast(bf16x8, braw[nt][1]);
        acc[mt][nt] = __builtin_amdgcn_mfma_f32_16x16x32_bf16(al, bh, acc[mt][nt], 0, 0, 0);
        acc[mt][nt] = __builtin_amdgcn_mfma_f32_16x16x32_bf16(ah, bl, acc[mt][nt], 0, 0, 0);
        acc[mt][nt] = __builtin_amdgcn_mfma_f32_16x16x32_bf16(ah, bh, acc[mt][nt], 0, 0, 0);
      }
    }
  }
#pragma unroll
  for (int mt = 0; mt < 4; ++mt) {
    int rowb = m0 + (wmt + mt) * 16 + ((l >> 4) << 2);
#pragma unroll
    for (int nt = 0; nt < 2; ++nt) {
      int colg = (ntile0 + nt) * 16 + (l & 15);
      float bv = 0.f;
      if (BIAS) bv = bias[colg];
#pragma unroll
      for (int i = 0; i < 4; ++i) {
        float v = acc[mt][nt][i] + bv;
        if (RELU) v = fmaxf(v, 0.f);
        size_t off = (size_t)(rowb + i) * M + colg;
        if constexpr (OUTM == 1) {
          unsigned short hh = f2bf(v);
          Chi[off] = hh;
          Clo[off] = f2bf(v - bf2f(hh));
        } else if constexpr (OUTM == 2) {
          Chi[off] = f2bf(v);
        } else {
          Cf[off] = v;
        }
      }
    }
  }
}

// ================= launch =================

static inline int nblk(long work, int tpb = TPB) { return (int)((work + tpb - 1) / tpb); }

extern "C" void kernel_launch(void* const* d_in, const int* in_sizes, int n_in,
                              void* d_out, int out_size, void* d_ws, size_t ws_size,
                              hipStream_t stream) {
  const float* x  = (const float*)d_in[0];
  const int*   ei = (const int*)d_in[1];
  const float* ew = (const float*)d_in[2];
  const int*  ngp = (const int*)d_in[3];
  const float* W1 = (const float*)d_in[4];
  const float* b1 = (const float*)d_in[5];
  const float* W2 = (const float*)d_in[6];
  const float* b2 = (const float*)d_in[7];
  const float* W3 = (const float*)d_in[8];
  const float* b3 = (const float*)d_in[9];
  float* out = (float*)d_out;

  const int n = in_sizes[0] / 128;  // 65536
  const int E = in_sizes[2];        // 1048576
  const int* row = ei;
  const int* col = ei + E;

  const size_t MB = 1024 * 1024;
  char* W8 = (char*)d_ws;
  int2* edat = (int2*)W8;                                       // 8 MB
  unsigned long long* pk = (unsigned long long*)(W8 + 8 * MB);  // n u64
  int* cnt   = (int*)(pk + n);
  int* ptrv  = cnt + n;
  int* cur   = ptrv + n + 1;
  int* bsum  = cur + n;
  int* boff  = bsum + 256;
  float* dis = (float*)(boff + 256);
  // region A (16..48 MB): t1 planes -> t2 bf16 -> t3 bf16 (sequentially dead)
  unsigned short* t1hi = (unsigned short*)(W8 + 16 * MB);  // 16 MB
  unsigned short* t1lo = (unsigned short*)(W8 + 32 * MB);  // 16 MB
  unsigned short* t2u  = (unsigned short*)(W8 + 16 * MB);  // 16 MB (alias t1hi)
  unsigned short* t3u  = (unsigned short*)(W8 + 16 * MB);  // 8 MB (alias t2u)
  // region B (56..120 MB): h1 planes -> h2 planes
  unsigned short* h1hi = (unsigned short*)(W8 + 56 * MB);  // 32 MB
  unsigned short* h1lo = (unsigned short*)(W8 + 88 * MB);  // 32 MB
  unsigned short* h2hi = (unsigned short*)(W8 + 56 * MB);  // 16 MB (alias h1hi)
  unsigned short* h2lo = (unsigned short*)(W8 + 72 * MB);  // 16 MB
  // W fragments (120 MB..)
  unsigned short* w1fh = (unsigned short*)(W8 + 120 * MB);
  unsigned short* w1fl = w1fh + 32768;
  unsigned short* w2fh = w1fl + 32768;
  unsigned short* w2fl = w2fh + 32768;
  unsigned short* w3fh = w2fl + 32768;
  unsigned short* w3fl = w3fh + 8192;

  // ---- CSR build + norms
  hipMemsetAsync(pk, 0, (size_t)n * 8, stream);
  k_count_deg<<<nblk(E), TPB, 0, stream>>>(col, ew, pk, E);
  k_decode<<<nblk(n), TPB, 0, stream>>>(pk, dis, cnt, n);
  k_reduceA<<<n / 256, 256, 0, stream>>>(cnt, bsum);
  k_scanB<<<1, 256, 0, stream>>>(bsum, boff);
  k_scanC<<<n / 256, 256, 0, stream>>>(cnt, boff, ptrv, cur, n);
  k_scatter_norm<<<nblk(E), TPB, 0, stream>>>(row, col, ew, dis, cur, edat, E);

  // ---- weight fragment prep
  k_wprep3<<<nblk(9216), TPB, 0, stream>>>(W1, W2, W3, w1fh, w1fl, w2fh, w2fl, w3fh, w3fl);

  // ---- layer 1: t1 = A(x) split planes; h1 = relu(t1@W1+b1) split planes
  k_gagg<32, false, false, false><<<nblk((long)n * 32), TPB, 0, stream>>>(
      ptrv, edat, x, dis, nullptr, t1hi, t1lo, n);
  {
    dim3 g(n / 128, 256 / 64);
    gemm_mfma<true, true, 1><<<g, 256, 0, stream>>>(
        t1hi, t1lo, w1fh, w1fl, b1, nullptr, h1hi, h1lo, 128, 256);
  }

  // ---- layer 2: t2 = h1@W2 (bf16); h2 = relu(A(t2)+b2) split planes
  {
    dim3 g(n / 128, 128 / 64);
    gemm_mfma<false, false, 2><<<g, 256, 0, stream>>>(
        h1hi, h1lo, w2fh, w2fl, nullptr, nullptr, t2u, nullptr, 256, 128);
  }
  k_gagg<16, true, true, true><<<nblk((long)n * 16), TPB, 0, stream>>>(
      ptrv, edat, t2u, dis, b2, h2hi, h2lo, n);

  // ---- layer 3: t3 = h2@W3 (bf16); out = A(t3)+b3 into padded layout
  {
    dim3 g(n / 128, 64 / 64);
    gemm_mfma<false, false, 2><<<g, 256, 0, stream>>>(
        h2hi, h2lo, w3fh, w3fl, nullptr, nullptr, t3u, nullptr, 128, 64);
  }
  const int nrows = out_size / 64;
  k_gagg_out<<<nblk((long)nrows * 8), TPB, 0, stream>>>(
      ptrv, edat, t3u, dis, b3, out, ngp, n, nrows);
}

// Round 8
// 373.264 us; speedup vs baseline: 12.6668x; 1.1394x over previous
//
#include <hip/hip_runtime.h>
#include <cstdint>

#define TPB 256

typedef __attribute__((ext_vector_type(8))) short bf16x8;
typedef __attribute__((ext_vector_type(4))) float f32x4;

__device__ inline unsigned short f2bf(float f) {
  unsigned u = __float_as_uint(f);
  u += 0x7fffu + ((u >> 16) & 1u);
  return (unsigned short)(u >> 16);
}
__device__ inline float bf2f(unsigned short h) {
  return __uint_as_float(((unsigned)h) << 16);
}

__device__ inline void gload_lds16(const void* g, void* l) {
  __builtin_amdgcn_global_load_lds(
      (const __attribute__((address_space(1))) unsigned int*)g,
      (__attribute__((address_space(3))) unsigned int*)l, 16, 0, 0);
}

// accumulate 8 bf16 features (packed in int4) scaled by nv into acc[0..7]
__device__ inline void acc_bf8(float* acc, int4 raw, float nv) {
  acc[0] += nv * __uint_as_float(((unsigned)raw.x) << 16);
  acc[1] += nv * __uint_as_float(((unsigned)raw.x) & 0xffff0000u);
  acc[2] += nv * __uint_as_float(((unsigned)raw.y) << 16);
  acc[3] += nv * __uint_as_float(((unsigned)raw.y) & 0xffff0000u);
  acc[4] += nv * __uint_as_float(((unsigned)raw.z) << 16);
  acc[5] += nv * __uint_as_float(((unsigned)raw.z) & 0xffff0000u);
  acc[6] += nv * __uint_as_float(((unsigned)raw.w) << 16);
  acc[7] += nv * __uint_as_float(((unsigned)raw.w) & 0xffff0000u);
}

// ================= x -> bf16 =================

__global__ void k_x2bf(const float* __restrict__ x, unsigned short* __restrict__ xb,
                       long total8) {
  long i = blockIdx.x * (long)blockDim.x + threadIdx.x;
  if (i >= total8) return;
  const float4* p = reinterpret_cast<const float4*>(x + i * 8);
  float4 a = p[0], b = p[1];
  unsigned short h[8];
  h[0] = f2bf(a.x); h[1] = f2bf(a.y); h[2] = f2bf(a.z); h[3] = f2bf(a.w);
  h[4] = f2bf(b.x); h[5] = f2bf(b.y); h[6] = f2bf(b.z); h[7] = f2bf(b.w);
  *reinterpret_cast<int4*>(xb + i * 8) = *(int4*)h;
}

// ================= 8-way replicated count+deg =================
// pk8[k][c] += (1<<40) | round(w * 2^32), k = blockIdx&7 (~XCD-local copy)

__global__ void k_count_deg8(const int* __restrict__ col, const float* __restrict__ w,
                             unsigned long long* __restrict__ pk8, int E, int n) {
  int e = blockIdx.x * blockDim.x + threadIdx.x;
  if (e >= E) return;
  int k = blockIdx.x & 7;
  int c = col[e];
  unsigned long long inc =
      (1ULL << 40) + (unsigned long long)(unsigned int)(w[e] * 4294967296.0f);
  atomicAdd(&pk8[(size_t)k * n + c], inc);
}

// per node: total count -> cnt, degree -> dis, per-copy exclusive prefix -> cum8
__global__ void k_decode8(const unsigned long long* __restrict__ pk8,
                          float* __restrict__ dis, int* __restrict__ cnt,
                          unsigned short* __restrict__ cum8, int n) {
  int i = blockIdx.x * blockDim.x + threadIdx.x;
  if (i >= n) return;
  unsigned long long tot = 0;
  int run = 0;
#pragma unroll
  for (int k = 0; k < 8; ++k) {
    unsigned long long v = pk8[(size_t)k * n + i];
    cum8[(size_t)k * n + i] = (unsigned short)run;
    run += (int)(v >> 40);
    tot += v & 0xFFFFFFFFFFULL;
  }
  cnt[i] = run;
  dis[i] = rsqrtf(1.0f + (float)tot * 2.3283064365386963e-10f);  // 2^-32
}

// ================= parallel scan =================

__global__ void k_reduceA(const int* __restrict__ cnt, int* __restrict__ bsum) {
  __shared__ int s[256];
  int t = threadIdx.x;
  s[t] = cnt[blockIdx.x * 256 + t];
  __syncthreads();
  for (int st = 128; st > 0; st >>= 1) {
    if (t < st) s[t] += s[t + st];
    __syncthreads();
  }
  if (t == 0) bsum[blockIdx.x] = s[0];
}

__global__ void k_scanB(const int* __restrict__ bsum, int* __restrict__ boff) {
  __shared__ int s[256];
  int t = threadIdx.x;
  int v = bsum[t];
  s[t] = v;
  __syncthreads();
  for (int st = 1; st < 256; st <<= 1) {
    int a = (t >= st) ? s[t - st] : 0;
    __syncthreads();
    s[t] += a;
    __syncthreads();
  }
  boff[t] = s[t] - v;
}

__global__ void k_scanC(const int* __restrict__ cnt, const int* __restrict__ boff,
                        int* __restrict__ ptr, int n) {
  __shared__ int s[256];
  int t = threadIdx.x;
  int i = blockIdx.x * 256 + t;
  int v = cnt[i];
  s[t] = v;
  __syncthreads();
  for (int st = 1; st < 256; st <<= 1) {
    int a = (t >= st) ? s[t - st] : 0;
    __syncthreads();
    s[t] += a;
    __syncthreads();
  }
  int excl = boff[blockIdx.x] + s[t] - v;
  ptr[i] = excl;
  if (i == n - 1) ptr[n] = excl + v;
}

// cur8[k][i] = ptr[i] + cum8[k][i]
__global__ void k_cur8(const int* __restrict__ ptr, const unsigned short* __restrict__ cum8,
                       int* __restrict__ cur8, int n) {
  int i = blockIdx.x * blockDim.x + threadIdx.x;
  if (i >= n) return;
  int k = blockIdx.y;
  cur8[(size_t)k * n + i] = ptr[i] + cum8[(size_t)k * n + i];
}

// ================= scatter with fused norm (8-way cur) =================

__global__ void k_scatter_norm8(const int* __restrict__ row, const int* __restrict__ col,
                                const float* __restrict__ w, const float* __restrict__ dis,
                                int* __restrict__ cur8, int2* __restrict__ edat,
                                int E, int n) {
  int e = blockIdx.x * blockDim.x + threadIdx.x;
  if (e >= E) return;
  int k = blockIdx.x & 7;
  int c = col[e];
  int r = row[e];
  float nv = dis[r] * w[e] * dis[c];
  int p = atomicAdd(&cur8[(size_t)k * n + c], 1);
  edat[p] = make_int2(r, __float_as_int(nv));
}

// ================= fused W fragment prep (hi/lo split kept) =================

__device__ inline void wprep_one(const float* __restrict__ W, unsigned short* __restrict__ Fh,
                                 unsigned short* __restrict__ Fl, int t, int M) {
  int l = t & 63;
  int rest = t >> 6;
  int nt16 = M >> 4;
  int c0t = rest % nt16;
  int ks = rest / nt16;
  int colg = c0t * 16 + (l & 15);
  int krow = (ks << 5) + ((l >> 4) << 3);
  size_t ob = (size_t)t * 8;
#pragma unroll
  for (int j = 0; j < 8; ++j) {
    float f = W[(size_t)(krow + j) * M + colg];
    unsigned short h = f2bf(f);
    Fh[ob + j] = h;
    Fl[ob + j] = f2bf(f - bf2f(h));
  }
}

__global__ void k_wprep3(const float* __restrict__ W1, const float* __restrict__ W2,
                         const float* __restrict__ W3,
                         unsigned short* __restrict__ f1h, unsigned short* __restrict__ f1l,
                         unsigned short* __restrict__ f2h, unsigned short* __restrict__ f2l,
                         unsigned short* __restrict__ f3h, unsigned short* __restrict__ f3l) {
  int t = blockIdx.x * blockDim.x + threadIdx.x;
  if (t < 4096) wprep_one(W1, f1h, f1l, t, 256);
  else if (t < 8192) wprep_one(W2, f2h, f2l, t - 4096, 128);
  else if (t < 9216) wprep_one(W3, f3h, f3l, t - 8192, 64);
}

// ================= gather aggregation (bf16 src, bf16 out) =================
// GL lanes/row, 8 bf16 features per lane (16B). F = GL*8.
// out[i] = ss*src[i] + sum norm*src[row]  (+bias, relu), f32 accumulate.

template<int GL, bool RELU, bool BIAS>
__global__ __launch_bounds__(256) void k_gagg(const int* __restrict__ ptr,
                                              const int2* __restrict__ edat,
                                              const unsigned short* __restrict__ src,
                                              const float* __restrict__ dis,
                                              const float* __restrict__ bias,
                                              unsigned short* __restrict__ outp, int n) {
  constexpr int F = GL * 8;
  constexpr int GPB = 256 / GL;
  const int gid = blockIdx.x * GPB + threadIdx.x / GL;
  const int lane = threadIdx.x % GL;
  if (gid >= n) return;
  const int e0 = ptr[gid], e1 = ptr[gid + 1];
  float d = dis[gid];
  float ss = d * d;
  float acc[8] = {0.f, 0.f, 0.f, 0.f, 0.f, 0.f, 0.f, 0.f};
  {
    int4 raw = *reinterpret_cast<const int4*>(src + (size_t)gid * F + lane * 8);
    acc_bf8(acc, raw, ss);
  }
  int e = e0;
  for (; e + 8 <= e1; e += 8) {
    int2 ed[8];
#pragma unroll
    for (int u = 0; u < 8; ++u) ed[u] = edat[e + u];
    int4 raw[8];
#pragma unroll
    for (int u = 0; u < 8; ++u)
      raw[u] = *reinterpret_cast<const int4*>(src + (size_t)ed[u].x * F + lane * 8);
#pragma unroll
    for (int u = 0; u < 8; ++u) acc_bf8(acc, raw[u], __int_as_float(ed[u].y));
  }
  for (; e + 4 <= e1; e += 4) {
    int2 ed[4];
#pragma unroll
    for (int u = 0; u < 4; ++u) ed[u] = edat[e + u];
    int4 raw[4];
#pragma unroll
    for (int u = 0; u < 4; ++u)
      raw[u] = *reinterpret_cast<const int4*>(src + (size_t)ed[u].x * F + lane * 8);
#pragma unroll
    for (int u = 0; u < 4; ++u) acc_bf8(acc, raw[u], __int_as_float(ed[u].y));
  }
  for (; e < e1; ++e) {
    int2 ed = edat[e];
    int4 raw = *reinterpret_cast<const int4*>(src + (size_t)ed.x * F + lane * 8);
    acc_bf8(acc, raw, __int_as_float(ed.y));
  }
  if (BIAS) {
#pragma unroll
    for (int j = 0; j < 8; ++j) acc[j] += bias[lane * 8 + j];
  }
  if (RELU) {
#pragma unroll
    for (int j = 0; j < 8; ++j) acc[j] = fmaxf(acc[j], 0.f);
  }
  unsigned short hv[8];
#pragma unroll
  for (int j = 0; j < 8; ++j) hv[j] = f2bf(acc[j]);
  *reinterpret_cast<int4*>(outp + (size_t)gid * F + lane * 8) = *(int4*)hv;
}

// Layer-3 aggregation: t3 bf16 [n,64] -> padded f32 out [ng, npg+1, 64], +b3.
__global__ __launch_bounds__(256) void k_gagg_out(const int* __restrict__ ptr,
                                                  const int2* __restrict__ edat,
                                                  const unsigned short* __restrict__ t3,
                                                  const float* __restrict__ dis,
                                                  const float* __restrict__ b3,
                                                  float* __restrict__ out,
                                                  const int* __restrict__ ngp,
                                                  int n, int nrows) {
  const int gid = blockIdx.x * 32 + threadIdx.x / 8;
  const int lane = threadIdx.x % 8;
  if (gid >= nrows) return;
  const int ng = *ngp;
  const int npg = n / ng;
  const int g = gid / (npg + 1);
  const int r = gid - g * (npg + 1);
  float acc[8] = {0.f, 0.f, 0.f, 0.f, 0.f, 0.f, 0.f, 0.f};
  if (r < npg) {
    const int i = g * npg + r;
    const int e0 = ptr[i], e1 = ptr[i + 1];
    float d = dis[i];
    float ss = d * d;
    int4 sraw = *reinterpret_cast<const int4*>(t3 + (size_t)i * 64 + lane * 8);
    acc_bf8(acc, sraw, ss);
    int e = e0;
    for (; e + 8 <= e1; e += 8) {
      int2 ed[8];
#pragma unroll
      for (int u = 0; u < 8; ++u) ed[u] = edat[e + u];
      int4 raw[8];
#pragma unroll
      for (int u = 0; u < 8; ++u)
        raw[u] = *reinterpret_cast<const int4*>(t3 + (size_t)ed[u].x * 64 + lane * 8);
#pragma unroll
      for (int u = 0; u < 8; ++u) acc_bf8(acc, raw[u], __int_as_float(ed[u].y));
    }
    for (; e + 4 <= e1; e += 4) {
      int2 ed[4];
#pragma unroll
      for (int u = 0; u < 4; ++u) ed[u] = edat[e + u];
      int4 raw[4];
#pragma unroll
      for (int u = 0; u < 4; ++u)
        raw[u] = *reinterpret_cast<const int4*>(t3 + (size_t)ed[u].x * 64 + lane * 8);
#pragma unroll
      for (int u = 0; u < 4; ++u) acc_bf8(acc, raw[u], __int_as_float(ed[u].y));
    }
    for (; e < e1; ++e) {
      int2 ed = edat[e];
      int4 raw = *reinterpret_cast<const int4*>(t3 + (size_t)ed.x * 64 + lane * 8);
      acc_bf8(acc, raw, __int_as_float(ed.y));
    }
#pragma unroll
    for (int j = 0; j < 8; ++j) acc[j] += b3[lane * 8 + j];
  }
  float4 o0 = make_float4(acc[0], acc[1], acc[2], acc[3]);
  float4 o1 = make_float4(acc[4], acc[5], acc[6], acc[7]);
  *reinterpret_cast<float4*>(out + (size_t)gid * 64 + lane * 8) = o0;
  *reinterpret_cast<float4*>(out + (size_t)gid * 64 + lane * 8 + 4) = o1;
}

// ================= bf16-A x split-W MFMA GEMM =================
// C[N,M] = A[N,K]*B[K,M]; A single bf16 plane, B hi/lo frag-ordered.
// BM=128, BN=64, 256 threads. A*B ~= A*Bh + A*Bl (2 MFMA/tile). bf16 out.

template<bool BIAS, bool RELU>
__global__ __launch_bounds__(256) void gemm_mfma(
    const unsigned short* __restrict__ A,
    const unsigned short* __restrict__ BfHi, const unsigned short* __restrict__ BfLo,
    const float* __restrict__ bias,
    unsigned short* __restrict__ C, int K, int M) {
  __shared__ unsigned short AL[4096];
  const int tid = threadIdx.x;
  const int l = tid & 63;
  const int w = tid >> 6;
  const int m0 = blockIdx.x * 128;
  const int wmt = (w >> 1) * 4;
  const int wn = (w & 1) * 2;
  const int ntile0 = blockIdx.y * 4 + wn;
  const int nt16 = M >> 4;

  f32x4 acc[4][2];
#pragma unroll
  for (int a = 0; a < 4; ++a)
#pragma unroll
    for (int b = 0; b < 2; ++b) acc[a][b] = f32x4{0.f, 0.f, 0.f, 0.f};

  const int nks = K >> 5;
  for (int ks = 0; ks < nks; ++ks) {
    if (ks) __syncthreads();
#pragma unroll
    for (int rr = 0; rr < 2; ++rr) {
      int s = rr * 256 + tid;
      int mt = s >> 6, sl = s & 63;
      size_t grow = (size_t)(m0 + mt * 16 + (sl & 15)) * K + (ks << 5) + ((sl >> 4) << 3);
      gload_lds16(A + grow, &AL[(size_t)s * 8]);
    }
    int4 braw[2][2];
#pragma unroll
    for (int nt = 0; nt < 2; ++nt) {
      size_t bidx = ((size_t)(ks * nt16 + ntile0 + nt) * 64 + l) * 8;
      braw[nt][0] = *reinterpret_cast<const int4*>(BfHi + bidx);
      braw[nt][1] = *reinterpret_cast<const int4*>(BfLo + bidx);
    }
    asm volatile("s_waitcnt vmcnt(0)" ::: "memory");
    __syncthreads();
#pragma unroll
    for (int mt = 0; mt < 4; ++mt) {
      int slot = (wmt + mt) * 64 + l;
      bf16x8 av = __builtin_bit_cast(bf16x8, *reinterpret_cast<const int4*>(&AL[(size_t)slot * 8]));
#pragma unroll
      for (int nt = 0; nt < 2; ++nt) {
        bf16x8 bh = __builtin_bit_cast(bf16x8, braw[nt][0]);
        bf16x8 bl = __builtin_bit_cast(bf16x8, braw[nt][1]);
        acc[mt][nt] = __builtin_amdgcn_mfma_f32_16x16x32_bf16(av, bl, acc[mt][nt], 0, 0, 0);
        acc[mt][nt] = __builtin_amdgcn_mfma_f32_16x16x32_bf16(av, bh, acc[mt][nt], 0, 0, 0);
      }
    }
  }
#pragma unroll
  for (int mt = 0; mt < 4; ++mt) {
    int rowb = m0 + (wmt + mt) * 16 + ((l >> 4) << 2);
#pragma unroll
    for (int nt = 0; nt < 2; ++nt) {
      int colg = (ntile0 + nt) * 16 + (l & 15);
      float bv = 0.f;
      if (BIAS) bv = bias[colg];
#pragma unroll
      for (int i = 0; i < 4; ++i) {
        float v = acc[mt][nt][i] + bv;
        if (RELU) v = fmaxf(v, 0.f);
        C[(size_t)(rowb + i) * M + colg] = f2bf(v);
      }
    }
  }
}

// ================= launch =================

static inline int nblk(long work, int tpb = TPB) { return (int)((work + tpb - 1) / tpb); }

extern "C" void kernel_launch(void* const* d_in, const int* in_sizes, int n_in,
                              void* d_out, int out_size, void* d_ws, size_t ws_size,
                              hipStream_t stream) {
  const float* x  = (const float*)d_in[0];
  const int*   ei = (const int*)d_in[1];
  const float* ew = (const float*)d_in[2];
  const int*  ngp = (const int*)d_in[3];
  const float* W1 = (const float*)d_in[4];
  const float* b1 = (const float*)d_in[5];
  const float* W2 = (const float*)d_in[6];
  const float* b2 = (const float*)d_in[7];
  const float* W3 = (const float*)d_in[8];
  const float* b3 = (const float*)d_in[9];
  float* out = (float*)d_out;

  const int n = in_sizes[0] / 128;  // 65536
  const int E = in_sizes[2];        // 1048576
  const int* row = ei;
  const int* col = ei + E;

  const size_t MB = 1024 * 1024;
  char* W8 = (char*)d_ws;
  int2* edat = (int2*)W8;                                       // 0..8 MB
  unsigned long long* pk8 = (unsigned long long*)(W8 + 8 * MB); // 4 MB (8n u64)
  int* cnt   = (int*)(W8 + 12 * MB);                            // n
  int* ptrv  = cnt + n;                                         // n+1
  int* bsum  = ptrv + n + 1;                                    // 256
  int* boff  = bsum + 256;                                      // 256
  float* dis = (float*)(boff + 256);                            // n
  unsigned short* cum8 = (unsigned short*)(dis + n);            // 8n ushort (1 MB)
  int* cur8  = (int*)(cum8 + 8 * (size_t)n);                    // 8n int (2 MB)
  unsigned short* xb  = (unsigned short*)(W8 + 16 * MB);        // 16 MB (x bf16)
  unsigned short* t1u = (unsigned short*)(W8 + 32 * MB);        // 16 MB
  unsigned short* t2u = (unsigned short*)(W8 + 32 * MB);        // alias
  unsigned short* t3u = (unsigned short*)(W8 + 32 * MB);        // alias
  unsigned short* h1u = (unsigned short*)(W8 + 48 * MB);        // 32 MB
  unsigned short* h2u = (unsigned short*)(W8 + 48 * MB);        // alias (h1 dead)
  unsigned short* w1fh = (unsigned short*)(W8 + 80 * MB);
  unsigned short* w1fl = w1fh + 32768;
  unsigned short* w2fh = w1fl + 32768;
  unsigned short* w2fl = w2fh + 32768;
  unsigned short* w3fh = w2fl + 32768;
  unsigned short* w3fl = w3fh + 8192;

  // ---- CSR build + norms (8-way replicated atomics)
  hipMemsetAsync(pk8, 0, (size_t)n * 8 * 8, stream);
  k_x2bf<<<nblk((long)n * 16), TPB, 0, stream>>>(x, xb, (long)n * 16);
  k_count_deg8<<<nblk(E), TPB, 0, stream>>>(col, ew, pk8, E, n);
  k_decode8<<<nblk(n), TPB, 0, stream>>>(pk8, dis, cnt, cum8, n);
  k_reduceA<<<n / 256, 256, 0, stream>>>(cnt, bsum);
  k_scanB<<<1, 256, 0, stream>>>(bsum, boff);
  k_scanC<<<n / 256, 256, 0, stream>>>(cnt, boff, ptrv, n);
  {
    dim3 g(nblk(n), 8);
    k_cur8<<<g, TPB, 0, stream>>>(ptrv, cum8, cur8, n);
  }
  k_scatter_norm8<<<nblk(E), TPB, 0, stream>>>(row, col, ew, dis, cur8, edat, E, n);

  // ---- weight fragment prep
  k_wprep3<<<nblk(9216), TPB, 0, stream>>>(W1, W2, W3, w1fh, w1fl, w2fh, w2fl, w3fh, w3fl);

  // ---- layer 1: t1 = A(xb); h1 = relu(t1@W1+b1)
  k_gagg<16, false, false><<<nblk((long)n * 16), TPB, 0, stream>>>(
      ptrv, edat, xb, dis, nullptr, t1u, n);
  {
    dim3 g(n / 128, 256 / 64);
    gemm_mfma<true, true><<<g, 256, 0, stream>>>(t1u, w1fh, w1fl, b1, h1u, 128, 256);
  }

  // ---- layer 2: t2 = h1@W2; h2 = relu(A(t2)+b2)
  {
    dim3 g(n / 128, 128 / 64);
    gemm_mfma<false, false><<<g, 256, 0, stream>>>(h1u, w2fh, w2fl, nullptr, t2u, 256, 128);
  }
  k_gagg<16, true, true><<<nblk((long)n * 16), TPB, 0, stream>>>(
      ptrv, edat, t2u, dis, b2, h2u, n);

  // ---- layer 3: t3 = h2@W3; out = A(t3)+b3 into padded layout
  {
    dim3 g(n / 128, 64 / 64);
    gemm_mfma<false, false><<<g, 256, 0, stream>>>(h2u, w3fh, w3fl, nullptr, t3u, 128, 64);
  }
  const int nrows = out_size / 64;
  k_gagg_out<<<nblk((long)nrows * 8), TPB, 0, stream>>>(
      ptrv, edat, t3u, dis, b3, out, ngp, n, nrows);
}